// Round 6
// baseline (380.256 us; speedup 1.0000x reference)
//
#include <hip/hip_runtime.h>
#include <hip/hip_bf16.h>

// ModifiedGAT, round 17 (resubmit of r16; bench infra failed — "container
// failed twice" — with no verification result. Kernel re-audited: LDS bounds,
// MFMA D-layout, alias ordering, barrier uniformity all check out.)
//  - gemm1 FUSED into agg0 (agg0g1_kernel): when a wave finishes a node's
//    layer-0 aggregation, its h1 row (256ch bf16) is in registers. Stage the
//    block's 4 rows in LDS (stride 264 to avoid bank conflicts), one barrier,
//    then wave j does the 4x16 quadrant of h1 @ W1 via 8 MFMA (A rows 4..15
//    zero), emits g1b + layer-1 logits. Deletes: mfma_gemm dispatch + gap,
//    25.6MB h1b write, 25.6MB h1b read.
//  - Aliases: g1b->xb (dead after gemm0), g2b->h0b (dead after agg0g1).
//  - Pipeline: memset | prep | blocksum | scan2 | scatter | gemm0 | agg0g1 |
//              agg1g2 | aggF  (9 dispatches).

typedef unsigned short ushort_t;
typedef __attribute__((ext_vector_type(8))) short short8;
typedef __attribute__((ext_vector_type(4))) float f32x4;

__device__ __forceinline__ float elu_f(float x){ return x > 0.f ? x : expm1f(x); }
__device__ __forceinline__ float lrelu_f(float x){ return x > 0.f ? x : 0.2f * x; }
__device__ __forceinline__ ushort_t f2b(float f){
  union { float f; unsigned u; } v; v.f = f;
  unsigned r = v.u + 0x7fff + ((v.u >> 16) & 1);   // round-to-nearest-even
  return (ushort_t)(r >> 16);
}
__device__ __forceinline__ float b2f_lo(unsigned v){
  union { unsigned u; float f; } c; c.u = v << 16; return c.f;
}
__device__ __forceinline__ float b2f_hi(unsigned v){
  union { unsigned u; float f; } c; c.u = v & 0xffff0000u; return c.f;
}

// ---------------- fused prep: hist + x->bf16 + weight transposes -------------
__global__ __launch_bounds__(256) void prep_kernel(const int* __restrict__ ei,
                                                   int* __restrict__ cnt,
                                                   const float4* __restrict__ x4,
                                                   ushort4* __restrict__ xb4, int n4,
                                                   const float* __restrict__ W0,
                                                   ushort_t* __restrict__ W0p,
                                                   const float* __restrict__ W1,
                                                   ushort_t* __restrict__ W1p,
                                                   const float* __restrict__ W2,
                                                   ushort_t* __restrict__ W2p,
                                                   int E, int Etot, int eb, int fb){
  int bid = blockIdx.x; int t = threadIdx.x;
  if(bid < eb){
    int e = bid * 256 + t;
    if(e < Etot){
      int d = (e < E) ? ei[E + e] : (e - E);
      atomicAdd(&cnt[d], 1);
    }
  } else if(bid < eb + fb){
    int i = (bid - eb) * 256 + t;
    if(i < n4){
      float4 v = x4[i];
      ushort4 o;
      o.x = f2b(v.x); o.y = f2b(v.y); o.z = f2b(v.z); o.w = f2b(v.w);
      xb4[i] = o;
    }
  } else {
    int r = bid - eb - fb;
    if(r < 256){            // W0: 256x256
      int i = r * 256 + t; int k = i >> 8, n = i & 255;
      W0p[(size_t)n * 256 + k] = f2b(W0[i]);
    } else if(r < 320){     // W1: 256x64
      int i = (r - 256) * 256 + t; int k = i >> 6, n = i & 63;
      W1p[(size_t)n * 256 + k] = f2b(W1[i]);
    } else {                // W2: 64x64
      int i = (r - 320) * 256 + t; int k = i >> 6, n = i & 63;
      W2p[(size_t)n * 64 + k] = f2b(W2[i]);
    }
  }
}

// ---------------- CSR scan -----------------------------------------------------
__global__ __launch_bounds__(256) void blocksum_kernel(const int* __restrict__ cnt,
                                                       int* __restrict__ bsum, int N){
  __shared__ int sm[256];
  int t = threadIdx.x;
  int i = blockIdx.x * 256 + t;
  sm[t] = (i < N) ? cnt[i] : 0;
  __syncthreads();
  for(int off = 128; off > 0; off >>= 1){
    if(t < off) sm[t] += sm[t + off];
    __syncthreads();
  }
  if(t == 0) bsum[blockIdx.x] = sm[0];
}

// scan2 with internal bsum prefix (scanb folded in); nb <= 256.
__global__ __launch_bounds__(256) void scan2_kernel(const int* __restrict__ cnt,
                                                    const int* __restrict__ bsum,
                                                    int* __restrict__ rowptr,
                                                    int* __restrict__ cursor,
                                                    int N, int Etot, int nb){
  __shared__ int sm[256];
  __shared__ int spfx;
  int t = threadIdx.x;
  int c = blockIdx.x;
  // prefix = sum of bsum[0..c)
  sm[t] = (t < c && t < nb) ? bsum[t] : 0;
  __syncthreads();
  for(int off = 128; off > 0; off >>= 1){
    if(t < off) sm[t] += sm[t + off];
    __syncthreads();
  }
  if(t == 0) spfx = sm[0];
  __syncthreads();
  int pfx = spfx;
  __syncthreads();
  // chunk-local exclusive scan
  int i = c * 256 + t;
  int v = (i < N) ? cnt[i] : 0;
  sm[t] = v;
  __syncthreads();
  for(int off = 1; off < 256; off <<= 1){
    int x = 0;
    if(t >= off) x = sm[t - off];
    __syncthreads();
    sm[t] += x;
    __syncthreads();
  }
  if(i < N){
    int ex = sm[t] - v + pfx;
    rowptr[i] = ex;
    cursor[i] = ex;
    if(i == N - 1) rowptr[N] = Etot;
  }
}

__global__ __launch_bounds__(256) void scatter_kernel(const int* __restrict__ ei,
                                                      int* __restrict__ cursor,
                                                      int* __restrict__ esrc,
                                                      int E, int Etot){
  int e = blockIdx.x * 256 + threadIdx.x;
  if(e >= Etot) return;
  int s, d;
  if(e < E){ s = ei[e]; d = ei[E + e]; } else { s = e - E; d = s; }
  int pos = atomicAdd(&cursor[d], 1);
  esrc[pos] = s;
}

// ---------------- GEMM0: h0b[M,256] = bf16(x[M,256] @ W0) + logits ----------
#define SKP 264   // padded LDS k-stride (shorts)
__global__ __launch_bounds__(256) void gemm0_kernel(const ushort_t* __restrict__ A,
                                                    const ushort_t* __restrict__ Bp,
                                                    ushort_t* __restrict__ h0b,
                                                    const float* __restrict__ asrc,
                                                    const float* __restrict__ adst,
                                                    float* __restrict__ als,
                                                    float* __restrict__ ald, int M){
  __shared__ ushort_t As[32 * SKP];
  int t = threadIdx.x;
  int row0 = blockIdx.x * 32;
  {
    int c = t;
    #pragma unroll
    for(int it = 0; it < 4; it++, c += 256){
      int r = c >> 5;
      int kc = (c & 31) << 3;
      int gr = row0 + r;
      short8 v = {};
      if(gr < M) v = *(const short8*)(A + (size_t)gr * 256 + kc);
      *(short8*)(As + r * SKP + kc) = v;
    }
  }
  __syncthreads();
  int wave = t >> 6, lane = t & 63;
  int m = lane & 15, q = lane >> 4;
  int colb = wave;                   // head
  const ushort_t* Bq = Bp + (size_t)(colb * 64 + m) * 256 + q * 8;
  const ushort_t* A0 = As + m * SKP + q * 8;
  const ushort_t* A1 = As + (16 + m) * SKP + q * 8;
  f32x4 acc[2][4] = {};
  for(int k0 = 0; k0 < 256; k0 += 32){
    short8 bv[4];
    #pragma unroll
    for(int j = 0; j < 4; j++) bv[j] = *(const short8*)(Bq + (size_t)j * 16 * 256 + k0);
    short8 a0 = *(const short8*)(A0 + k0);
    short8 a1 = *(const short8*)(A1 + k0);
    #pragma unroll
    for(int j = 0; j < 4; j++){
      acc[0][j] = __builtin_amdgcn_mfma_f32_16x16x32_bf16(a0, bv[j], acc[0][j], 0, 0, 0);
      acc[1][j] = __builtin_amdgcn_mfma_f32_16x16x32_bf16(a1, bv[j], acc[1][j], 0, 0, 0);
    }
  }
  #pragma unroll
  for(int rt = 0; rt < 2; rt++){
    #pragma unroll
    for(int j = 0; j < 4; j++){
      int col = colb * 64 + j * 16 + m;
      #pragma unroll
      for(int i = 0; i < 4; i++){
        int gr = row0 + rt * 16 + q * 4 + i;
        if(gr < M) h0b[(size_t)gr * 256 + col] = f2b(acc[rt][j][i]);
      }
    }
    float vs[4] = {0,0,0,0}, vd[4] = {0,0,0,0};
    #pragma unroll
    for(int j = 0; j < 4; j++){
      int col = colb * 64 + j * 16 + m;
      float a_s = asrc[col], a_d = adst[col];
      #pragma unroll
      for(int i = 0; i < 4; i++){
        vs[i] = fmaf(acc[rt][j][i], a_s, vs[i]);
        vd[i] = fmaf(acc[rt][j][i], a_d, vd[i]);
      }
    }
    #pragma unroll
    for(int off = 8; off > 0; off >>= 1){
      #pragma unroll
      for(int i = 0; i < 4; i++){
        vs[i] += __shfl_down(vs[i], off, 16);
        vd[i] += __shfl_down(vd[i], off, 16);
      }
    }
    if(m == 0){
      #pragma unroll
      for(int i = 0; i < 4; i++){
        int gr = row0 + rt * 16 + q * 4 + i;
        if(gr < M){
          als[(size_t)gr * 4 + colb] = vs[i];
          ald[(size_t)gr * 4 + colb] = vd[i];
        }
      }
    }
  }
}

// ---------------- agg0 + GEMM1 fused -----------------------------------------
// Phase 1: wave w aggregates node nbase+w (r14 batched-MLP gather), h1 row
//          (256ch bf16) -> LDS (padded stride).
// Phase 2: wave j computes cols j*16..j*16+15 of h1[4 rows] @ W1 via 8 MFMA
//          (A rows 4..15 zero); emits g1b + layer-1 logits.
#define SKP2 264
__global__ __launch_bounds__(256, 8) void agg0g1_kernel(const int* __restrict__ rowptr,
                                                        const int* __restrict__ esrc,
                                                        const uint2* __restrict__ h0b2,
                                                        const float4* __restrict__ als4,
                                                        const float4* __restrict__ ald4,
                                                        const float4* __restrict__ b4,
                                                        const ushort_t* __restrict__ W1p,
                                                        const float* __restrict__ as1,
                                                        const float* __restrict__ ad1,
                                                        ushort_t* __restrict__ g1b,
                                                        float* __restrict__ als1,
                                                        float* __restrict__ ald1, int N){
  __shared__ ushort_t Hs[4 * SKP2];
  __shared__ float aps[4][4], apd[4][4];
  int t = threadIdx.x;
  int lane = t & 63;
  int wave = t >> 6;
  int nbase = blockIdx.x * 4;
  int n = nbase + wave;
  uint2 o; o.x = 0u; o.y = 0u;
  if(n < N){
    int h = lane >> 4;
    int beg = rowptr[n], end = rowptr[n + 1];
    float adh = ((const float*)(ald4 + n))[h];
    float4 acc = make_float4(0.f, 0.f, 0.f, 0.f);
    float den = 0.f;
    for(int c0 = beg; c0 < end; c0 += 16){
      int e = c0 + (lane & 15);
      int s = n; float w = 0.f;
      if(e < end){
        s = esrc[e];
        w = expf(lrelu_f(((const float*)(als4 + s))[h] + adh));
      }
      int rem = end - c0;                 // wave-uniform
      if(rem > 16) rem = 16;
      #pragma unroll
      for(int g = 0; g < 4; g++){
        if(g * 4 < rem){
          int si[4]; float wi[4]; uint2 v[4];
          #pragma unroll
          for(int ii = 0; ii < 4; ii++){
            int idx = (lane & 48) + g * 4 + ii;
            si[ii] = __shfl(s, idx, 64);
            wi[ii] = __shfl(w, idx, 64);
          }
          #pragma unroll
          for(int ii = 0; ii < 4; ii++)
            v[ii] = h0b2[((size_t)si[ii] << 6) + lane];
          #pragma unroll
          for(int ii = 0; ii < 4; ii++){
            acc.x = fmaf(wi[ii], b2f_lo(v[ii].x), acc.x);
            acc.y = fmaf(wi[ii], b2f_hi(v[ii].x), acc.y);
            acc.z = fmaf(wi[ii], b2f_lo(v[ii].y), acc.z);
            acc.w = fmaf(wi[ii], b2f_hi(v[ii].y), acc.w);
            den += wi[ii];
          }
        }
      }
    }
    float inv = 1.f / (den + 1e-16f);
    float4 bb = b4[lane];
    float v0 = elu_f(acc.x * inv + bb.x);
    float v1 = elu_f(acc.y * inv + bb.y);
    float v2 = elu_f(acc.z * inv + bb.z);
    float v3 = elu_f(acc.w * inv + bb.w);
    o.x = (unsigned)f2b(v0) | ((unsigned)f2b(v1) << 16);
    o.y = (unsigned)f2b(v2) | ((unsigned)f2b(v3) << 16);
  }
  *(uint2*)(Hs + wave * SKP2 + lane * 4) = o;
  __syncthreads();
  // ---- phase 2: g1[4x64] = h1[4x256] @ W1 (per-wave 16-col quadrant) ----
  int m = lane & 15, q = lane >> 4;
  const ushort_t* Bw = W1p + (size_t)(wave * 16 + m) * 256 + q * 8;
  f32x4 acc1 = {};
  #pragma unroll
  for(int k0 = 0; k0 < 256; k0 += 32){
    short8 av = {};
    if(m < 4) av = *(const short8*)(Hs + m * SKP2 + q * 8 + k0);
    short8 bv = *(const short8*)(Bw + k0);
    acc1 = __builtin_amdgcn_mfma_f32_16x16x32_bf16(av, bv, acc1, 0, 0, 0);
  }
  // D rows 0..3 (nodes nbase+i, reg i) live in q==0 lanes, col = wave*16+m
  if(q == 0){
    #pragma unroll
    for(int i = 0; i < 4; i++){
      int gn = nbase + i;
      if(gn < N) g1b[(size_t)gn * 64 + wave * 16 + m] = f2b(acc1[i]);
    }
  }
  float a_s = as1[wave * 16 + m], a_d = ad1[wave * 16 + m];
  float vs[4], vd[4];
  #pragma unroll
  for(int i = 0; i < 4; i++){
    vs[i] = acc1[i] * a_s;
    vd[i] = acc1[i] * a_d;
  }
  #pragma unroll
  for(int off = 8; off > 0; off >>= 1){
    #pragma unroll
    for(int i = 0; i < 4; i++){
      vs[i] += __shfl_down(vs[i], off, 16);
      vd[i] += __shfl_down(vd[i], off, 16);
    }
  }
  if(lane == 0){
    #pragma unroll
    for(int i = 0; i < 4; i++){ aps[wave][i] = vs[i]; apd[wave][i] = vd[i]; }
  }
  __syncthreads();
  if(t < 4){
    int gn = nbase + t;
    if(gn < N){
      als1[gn] = aps[0][t] + aps[1][t] + aps[2][t] + aps[3][t];
      ald1[gn] = apd[0][t] + apd[1][t] + apd[2][t] + apd[3][t];
    }
  }
}

// ---------------- agg1-L1 + GEMM2 fused --------------------------------------
// L1 agg: one node per 16-lane group (4 nodes/wave, 16 nodes/block).
#define H2S 72    // LDS h2 tile k-stride (shorts)
__global__ __launch_bounds__(256, 8) void agg1g2_kernel(const int* __restrict__ rowptr,
                                                        const int* __restrict__ esrc,
                                                        const uint2* __restrict__ g1b2,
                                                        const float* __restrict__ als1,
                                                        const float* __restrict__ ald1,
                                                        const float* __restrict__ b1,
                                                        const ushort_t* __restrict__ W2p,
                                                        const float* __restrict__ as2,
                                                        const float* __restrict__ ad2,
                                                        ushort_t* __restrict__ g2b,
                                                        float* __restrict__ als2,
                                                        float* __restrict__ ald2, int N){
  __shared__ ushort_t Hs[16 * H2S];
  __shared__ float aps[4][16], apd[4][16];
  int t = threadIdx.x;
  int wave = t >> 6, lane = t & 63;
  int nbase = blockIdx.x * 16;
  int g = lane >> 4;                 // group in wave
  int p = lane & 15;                 // lane in group
  int n = nbase + wave * 4 + g;
  int nl = wave * 4 + g;
  if(n < N){
    int beg = rowptr[n], end = rowptr[n + 1];
    float ad = ald1[n];
    float4 acc = make_float4(0.f, 0.f, 0.f, 0.f);
    float den = 0.f;
    for(int c0 = beg; c0 < end; c0 += 16){
      int e = c0 + p;
      int s = n; float w = 0.f;
      if(e < end){
        s = esrc[e];
        w = expf(lrelu_f(als1[s] + ad));
      }
      int rem = end - c0;            // group-uniform
      if(rem > 16) rem = 16;
      #pragma unroll
      for(int gg = 0; gg < 4; gg++){
        if(gg * 4 < rem){
          #pragma unroll
          for(int ii = 0; ii < 4; ii++){
            int i = gg * 4 + ii;
            int idx = (lane & 48) + i;
            int si = __shfl(s, idx, 64);
            float wi = __shfl(w, idx, 64);
            uint2 v = g1b2[((size_t)si << 4) + p];
            acc.x = fmaf(wi, b2f_lo(v.x), acc.x);
            acc.y = fmaf(wi, b2f_hi(v.x), acc.y);
            acc.z = fmaf(wi, b2f_lo(v.y), acc.z);
            acc.w = fmaf(wi, b2f_hi(v.y), acc.w);
            den += wi;
          }
        }
      }
    }
    float inv = 1.f / (den + 1e-16f);
    float4 bb = ((const float4*)b1)[p];
    unsigned o0 = (unsigned)f2b(elu_f(acc.x * inv + bb.x)) |
                  ((unsigned)f2b(elu_f(acc.y * inv + bb.y)) << 16);
    unsigned o1 = (unsigned)f2b(elu_f(acc.z * inv + bb.z)) |
                  ((unsigned)f2b(elu_f(acc.w * inv + bb.w)) << 16);
    uint2 ov; ov.x = o0; ov.y = o1;
    *(uint2*)(Hs + nl * H2S + p * 4) = ov;
  }
  __syncthreads();
  int m = lane & 15, q = lane >> 4;
  const ushort_t* Bw = W2p + (size_t)(wave * 16 + m) * 64 + q * 8;
  const ushort_t* Aw = Hs + m * H2S + q * 8;
  f32x4 acc = {};
  #pragma unroll
  for(int k0 = 0; k0 < 64; k0 += 32){
    short8 av = *(const short8*)(Aw + k0);
    short8 bv = *(const short8*)(Bw + k0);
    acc = __builtin_amdgcn_mfma_f32_16x16x32_bf16(av, bv, acc, 0, 0, 0);
  }
  float a_s = as2[wave * 16 + m], a_d = ad2[wave * 16 + m];
  float vs[4], vd[4];
  #pragma unroll
  for(int i = 0; i < 4; i++){
    int gn = nbase + q * 4 + i;
    if(gn < N) g2b[(size_t)gn * 64 + wave * 16 + m] = f2b(acc[i]);
    vs[i] = acc[i] * a_s;
    vd[i] = acc[i] * a_d;
  }
  #pragma unroll
  for(int off = 8; off > 0; off >>= 1){
    #pragma unroll
    for(int i = 0; i < 4; i++){
      vs[i] += __shfl_down(vs[i], off, 16);
      vd[i] += __shfl_down(vd[i], off, 16);
    }
  }
  if(m == 0){
    #pragma unroll
    for(int i = 0; i < 4; i++){
      aps[wave][q * 4 + i] = vs[i];
      apd[wave][q * 4 + i] = vd[i];
    }
  }
  __syncthreads();
  if(t < 16){
    int gn = nbase + t;
    if(gn < N){
      als2[gn] = aps[0][t] + aps[1][t] + aps[2][t] + aps[3][t];
      ald2[gn] = apd[0][t] + apd[1][t] + apd[2][t] + apd[3][t];
    }
  }
}

// ---------------- final agg (layer 2): 16-lane group per node, fp32 out ------
__global__ __launch_bounds__(256, 8) void aggF_kernel(const int* __restrict__ rowptr,
                                                      const int* __restrict__ esrc,
                                                      const uint2* __restrict__ gb2,
                                                      const float* __restrict__ als,
                                                      const float* __restrict__ ald,
                                                      const float* __restrict__ b,
                                                      float4* __restrict__ outp, int N){
  int t = threadIdx.x;
  int lane = t & 63;
  int g = lane >> 4;
  int p = lane & 15;
  int n = blockIdx.x * 16 + (t >> 6) * 4 + g;
  if(n >= N) return;
  int beg = rowptr[n], end = rowptr[n + 1];
  float ad = ald[n];
  float4 acc = make_float4(0.f, 0.f, 0.f, 0.f);
  float den = 0.f;
  for(int c0 = beg; c0 < end; c0 += 16){
    int e = c0 + p;
    int s = n; float w = 0.f;
    if(e < end){
      s = esrc[e];
      w = expf(lrelu_f(als[s] + ad));
    }
    int rem = end - c0;              // group-uniform
    if(rem > 16) rem = 16;
    #pragma unroll
    for(int gg = 0; gg < 4; gg++){
      if(gg * 4 < rem){
        #pragma unroll
        for(int ii = 0; ii < 4; ii++){
          int i = gg * 4 + ii;
          int idx = (lane & 48) + i;
          int si = __shfl(s, idx, 64);
          float wi = __shfl(w, idx, 64);
          uint2 v = gb2[((size_t)si << 4) + p];
          acc.x = fmaf(wi, b2f_lo(v.x), acc.x);
          acc.y = fmaf(wi, b2f_hi(v.x), acc.y);
          acc.z = fmaf(wi, b2f_lo(v.y), acc.z);
          acc.w = fmaf(wi, b2f_hi(v.y), acc.w);
          den += wi;
        }
      }
    }
  }
  float inv = 1.f / (den + 1e-16f);
  float4 bb = ((const float4*)b)[p];
  float4 o;
  o.x = elu_f(acc.x * inv + bb.x);
  o.y = elu_f(acc.y * inv + bb.y);
  o.z = elu_f(acc.z * inv + bb.z);
  o.w = elu_f(acc.w * inv + bb.w);
  outp[((size_t)n << 4) + p] = o;
}

extern "C" void kernel_launch(void* const* d_in, const int* in_sizes, int n_in,
                              void* d_out, int out_size, void* d_ws, size_t ws_size,
                              hipStream_t stream){
  const float* x   = (const float*)d_in[0];
  const int*   ei  = (const int*)d_in[1];
  const float* W0  = (const float*)d_in[2];
  const float* as0 = (const float*)d_in[3];
  const float* ad0 = (const float*)d_in[4];
  const float* b0  = (const float*)d_in[5];
  const float* W1  = (const float*)d_in[6];
  const float* as1 = (const float*)d_in[7];
  const float* ad1 = (const float*)d_in[8];
  const float* b1  = (const float*)d_in[9];
  const float* W2  = (const float*)d_in[10];
  const float* as2 = (const float*)d_in[11];
  const float* ad2 = (const float*)d_in[12];
  const float* b2  = (const float*)d_in[13];
  int N = in_sizes[0] / 256;
  int E = in_sizes[1] / 2;
  int Etot = E + N;

  size_t off = 0;
  auto alc = [&](size_t bytes) -> char* {
    char* p = (char*)d_ws + off;
    off += (bytes + 255) & ~(size_t)255;
    return p;
  };
  ushort_t* xb    = (ushort_t*)alc((size_t)N * 256 * 2); // x bf16; g1b aliases
  ushort_t* h0b   = (ushort_t*)alc((size_t)N * 256 * 2); // h0 bf16; g2b aliases
  float*    als   = (float*)alc((size_t)N * 4 * 4);
  float*    ald   = (float*)alc((size_t)N * 4 * 4);
  float*    als1  = (float*)alc((size_t)N * 4);
  float*    ald1  = (float*)alc((size_t)N * 4);
  float*    als2  = (float*)alc((size_t)N * 4);
  float*    ald2  = (float*)alc((size_t)N * 4);
  int*      esrc  = (int*)alc((size_t)Etot * 4);
  int*      rowptr= (int*)alc((size_t)(N + 1) * 4);
  int*      cnt   = (int*)alc((size_t)N * 4);
  int*      cursor= (int*)alc((size_t)N * 4);
  int*      bsum  = (int*)alc(256 * 4);
  ushort_t* W0p   = (ushort_t*)alc(256 * 256 * 2);
  ushort_t* W1p   = (ushort_t*)alc(256 * 64 * 2);
  ushort_t* W2p   = (ushort_t*)alc(64 * 64 * 2);

  ushort_t* g1b = xb;                      // xb dead after gemm0
  ushort_t* g2b = h0b;                     // h0b dead after agg0g1

  int nb = (N + 255) / 256;                // <= 256 chunks
  int eb = (Etot + 255) / 256;
  int fb = (N * 64 + 255) / 256;
  int g0b = (N + 31) / 32;
  int tb = (N + 15) / 16;
  int ab = (N + 3) / 4;
  int ab16 = (N + 15) / 16;

  // ---- prep + CSR build ----
  hipMemsetAsync(cnt, 0, (size_t)N * 4, stream);
  prep_kernel<<<eb + fb + 336, 256, 0, stream>>>(ei, cnt, (const float4*)x,
                                                 (ushort4*)xb, N * 64,
                                                 W0, W0p, W1, W1p, W2, W2p,
                                                 E, Etot, eb, fb);
  blocksum_kernel<<<nb, 256, 0, stream>>>(cnt, bsum, N);
  scan2_kernel<<<nb, 256, 0, stream>>>(cnt, bsum, rowptr, cursor, N, Etot, nb);
  scatter_kernel<<<eb, 256, 0, stream>>>(ei, cursor, esrc, E, Etot);

  // ---- Layer 0 GEMM ----
  gemm0_kernel<<<g0b, 256, 0, stream>>>(xb, W0p, h0b, as0, ad0, als, ald, N);

  // ---- Layer 0 agg + Layer 1 GEMM (fused) ----
  agg0g1_kernel<<<ab, 256, 0, stream>>>(rowptr, esrc, (const uint2*)h0b,
                                        (const float4*)als, (const float4*)ald,
                                        (const float4*)b0, W1p, as1, ad1,
                                        g1b, als1, ald1, N);

  // ---- Layer 1 agg + Layer 2 GEMM (fused) ----
  agg1g2_kernel<<<tb, 256, 0, stream>>>(rowptr, esrc, (const uint2*)g1b,
                                        als1, ald1, b1, W2p, as2, ad2,
                                        g2b, als2, ald2, N);

  // ---- Layer 2 agg -> output ----
  aggF_kernel<<<ab16, 256, 0, stream>>>(rowptr, esrc, (const uint2*)g2b,
                                        als2, ald2, b2, (float4*)d_out, N);
}

// Round 7
// 360.017 us; speedup vs baseline: 1.0562x; 1.0562x over previous
//
#include <hip/hip_runtime.h>
#include <hip/hip_bf16.h>

// ModifiedGAT, round 18:
//  - r16/r17 post-mortem: fusion correct (WRITE 25000->7034 KB as predicted)
//    but agg0g1 104us vs 65: barrier convoy (1 node/wave -> block gather =
//    max(4 node degrees), waves idle at barrier; BW 3.66->2.11 TB/s) + phase-2
//    waste (12/16 zero rows, 32KB W1p per 4-node block = 400MB L2).
//  - r18 fix: 16 nodes/block, each wave gathers 4 nodes SEQUENTIALLY before
//    the barrier (CLT halves relative variance -> utilization 0.79->0.92);
//    phase-2 uses the full 16-row A tile (0 dead rows), 4x fewer blocks
//    (W1p L2 traffic 100MB), epilogue = agg1g2's proven aps[4][16] pattern.
//  - Pipeline: memset | prep | blocksum | scan2 | scatter | gemm0 | agg0g1 |
//              agg1g2 | aggF  (9 dispatches).

typedef unsigned short ushort_t;
typedef __attribute__((ext_vector_type(8))) short short8;
typedef __attribute__((ext_vector_type(4))) float f32x4;

__device__ __forceinline__ float elu_f(float x){ return x > 0.f ? x : expm1f(x); }
__device__ __forceinline__ float lrelu_f(float x){ return x > 0.f ? x : 0.2f * x; }
__device__ __forceinline__ ushort_t f2b(float f){
  union { float f; unsigned u; } v; v.f = f;
  unsigned r = v.u + 0x7fff + ((v.u >> 16) & 1);   // round-to-nearest-even
  return (ushort_t)(r >> 16);
}
__device__ __forceinline__ float b2f_lo(unsigned v){
  union { unsigned u; float f; } c; c.u = v << 16; return c.f;
}
__device__ __forceinline__ float b2f_hi(unsigned v){
  union { unsigned u; float f; } c; c.u = v & 0xffff0000u; return c.f;
}

// ---------------- fused prep: hist + x->bf16 + weight transposes -------------
__global__ __launch_bounds__(256) void prep_kernel(const int* __restrict__ ei,
                                                   int* __restrict__ cnt,
                                                   const float4* __restrict__ x4,
                                                   ushort4* __restrict__ xb4, int n4,
                                                   const float* __restrict__ W0,
                                                   ushort_t* __restrict__ W0p,
                                                   const float* __restrict__ W1,
                                                   ushort_t* __restrict__ W1p,
                                                   const float* __restrict__ W2,
                                                   ushort_t* __restrict__ W2p,
                                                   int E, int Etot, int eb, int fb){
  int bid = blockIdx.x; int t = threadIdx.x;
  if(bid < eb){
    int e = bid * 256 + t;
    if(e < Etot){
      int d = (e < E) ? ei[E + e] : (e - E);
      atomicAdd(&cnt[d], 1);
    }
  } else if(bid < eb + fb){
    int i = (bid - eb) * 256 + t;
    if(i < n4){
      float4 v = x4[i];
      ushort4 o;
      o.x = f2b(v.x); o.y = f2b(v.y); o.z = f2b(v.z); o.w = f2b(v.w);
      xb4[i] = o;
    }
  } else {
    int r = bid - eb - fb;
    if(r < 256){            // W0: 256x256
      int i = r * 256 + t; int k = i >> 8, n = i & 255;
      W0p[(size_t)n * 256 + k] = f2b(W0[i]);
    } else if(r < 320){     // W1: 256x64
      int i = (r - 256) * 256 + t; int k = i >> 6, n = i & 63;
      W1p[(size_t)n * 256 + k] = f2b(W1[i]);
    } else {                // W2: 64x64
      int i = (r - 320) * 256 + t; int k = i >> 6, n = i & 63;
      W2p[(size_t)n * 64 + k] = f2b(W2[i]);
    }
  }
}

// ---------------- CSR scan -----------------------------------------------------
__global__ __launch_bounds__(256) void blocksum_kernel(const int* __restrict__ cnt,
                                                       int* __restrict__ bsum, int N){
  __shared__ int sm[256];
  int t = threadIdx.x;
  int i = blockIdx.x * 256 + t;
  sm[t] = (i < N) ? cnt[i] : 0;
  __syncthreads();
  for(int off = 128; off > 0; off >>= 1){
    if(t < off) sm[t] += sm[t + off];
    __syncthreads();
  }
  if(t == 0) bsum[blockIdx.x] = sm[0];
}

// scan2 with internal bsum prefix (scanb folded in); nb <= 256.
__global__ __launch_bounds__(256) void scan2_kernel(const int* __restrict__ cnt,
                                                    const int* __restrict__ bsum,
                                                    int* __restrict__ rowptr,
                                                    int* __restrict__ cursor,
                                                    int N, int Etot, int nb){
  __shared__ int sm[256];
  __shared__ int spfx;
  int t = threadIdx.x;
  int c = blockIdx.x;
  // prefix = sum of bsum[0..c)
  sm[t] = (t < c && t < nb) ? bsum[t] : 0;
  __syncthreads();
  for(int off = 128; off > 0; off >>= 1){
    if(t < off) sm[t] += sm[t + off];
    __syncthreads();
  }
  if(t == 0) spfx = sm[0];
  __syncthreads();
  int pfx = spfx;
  __syncthreads();
  // chunk-local exclusive scan
  int i = c * 256 + t;
  int v = (i < N) ? cnt[i] : 0;
  sm[t] = v;
  __syncthreads();
  for(int off = 1; off < 256; off <<= 1){
    int x = 0;
    if(t >= off) x = sm[t - off];
    __syncthreads();
    sm[t] += x;
    __syncthreads();
  }
  if(i < N){
    int ex = sm[t] - v + pfx;
    rowptr[i] = ex;
    cursor[i] = ex;
    if(i == N - 1) rowptr[N] = Etot;
  }
}

__global__ __launch_bounds__(256) void scatter_kernel(const int* __restrict__ ei,
                                                      int* __restrict__ cursor,
                                                      int* __restrict__ esrc,
                                                      int E, int Etot){
  int e = blockIdx.x * 256 + threadIdx.x;
  if(e >= Etot) return;
  int s, d;
  if(e < E){ s = ei[e]; d = ei[E + e]; } else { s = e - E; d = s; }
  int pos = atomicAdd(&cursor[d], 1);
  esrc[pos] = s;
}

// ---------------- GEMM0: h0b[M,256] = bf16(x[M,256] @ W0) + logits ----------
#define SKP 264   // padded LDS k-stride (shorts)
__global__ __launch_bounds__(256) void gemm0_kernel(const ushort_t* __restrict__ A,
                                                    const ushort_t* __restrict__ Bp,
                                                    ushort_t* __restrict__ h0b,
                                                    const float* __restrict__ asrc,
                                                    const float* __restrict__ adst,
                                                    float* __restrict__ als,
                                                    float* __restrict__ ald, int M){
  __shared__ ushort_t As[32 * SKP];
  int t = threadIdx.x;
  int row0 = blockIdx.x * 32;
  {
    int c = t;
    #pragma unroll
    for(int it = 0; it < 4; it++, c += 256){
      int r = c >> 5;
      int kc = (c & 31) << 3;
      int gr = row0 + r;
      short8 v = {};
      if(gr < M) v = *(const short8*)(A + (size_t)gr * 256 + kc);
      *(short8*)(As + r * SKP + kc) = v;
    }
  }
  __syncthreads();
  int wave = t >> 6, lane = t & 63;
  int m = lane & 15, q = lane >> 4;
  int colb = wave;                   // head
  const ushort_t* Bq = Bp + (size_t)(colb * 64 + m) * 256 + q * 8;
  const ushort_t* A0 = As + m * SKP + q * 8;
  const ushort_t* A1 = As + (16 + m) * SKP + q * 8;
  f32x4 acc[2][4] = {};
  for(int k0 = 0; k0 < 256; k0 += 32){
    short8 bv[4];
    #pragma unroll
    for(int j = 0; j < 4; j++) bv[j] = *(const short8*)(Bq + (size_t)j * 16 * 256 + k0);
    short8 a0 = *(const short8*)(A0 + k0);
    short8 a1 = *(const short8*)(A1 + k0);
    #pragma unroll
    for(int j = 0; j < 4; j++){
      acc[0][j] = __builtin_amdgcn_mfma_f32_16x16x32_bf16(a0, bv[j], acc[0][j], 0, 0, 0);
      acc[1][j] = __builtin_amdgcn_mfma_f32_16x16x32_bf16(a1, bv[j], acc[1][j], 0, 0, 0);
    }
  }
  #pragma unroll
  for(int rt = 0; rt < 2; rt++){
    #pragma unroll
    for(int j = 0; j < 4; j++){
      int col = colb * 64 + j * 16 + m;
      #pragma unroll
      for(int i = 0; i < 4; i++){
        int gr = row0 + rt * 16 + q * 4 + i;
        if(gr < M) h0b[(size_t)gr * 256 + col] = f2b(acc[rt][j][i]);
      }
    }
    float vs[4] = {0,0,0,0}, vd[4] = {0,0,0,0};
    #pragma unroll
    for(int j = 0; j < 4; j++){
      int col = colb * 64 + j * 16 + m;
      float a_s = asrc[col], a_d = adst[col];
      #pragma unroll
      for(int i = 0; i < 4; i++){
        vs[i] = fmaf(acc[rt][j][i], a_s, vs[i]);
        vd[i] = fmaf(acc[rt][j][i], a_d, vd[i]);
      }
    }
    #pragma unroll
    for(int off = 8; off > 0; off >>= 1){
      #pragma unroll
      for(int i = 0; i < 4; i++){
        vs[i] += __shfl_down(vs[i], off, 16);
        vd[i] += __shfl_down(vd[i], off, 16);
      }
    }
    if(m == 0){
      #pragma unroll
      for(int i = 0; i < 4; i++){
        int gr = row0 + rt * 16 + q * 4 + i;
        if(gr < M){
          als[(size_t)gr * 4 + colb] = vs[i];
          ald[(size_t)gr * 4 + colb] = vd[i];
        }
      }
    }
  }
}

// ---------------- agg0 + GEMM1 fused (16 nodes/block) ------------------------
// Phase 1: wave w gathers nodes nbase+w*4..w*4+3 sequentially (full-wave r14
//          body per node); h1 rows -> LDS (padded stride).
// Phase 2: full 16x256 A tile; wave w computes cols w*16..w*16+15 of
//          h1[16] @ W1 via 8 MFMA; emits g1b + layer-1 logits.
#define SKP2 264
__global__ __launch_bounds__(256, 8) void agg0g1_kernel(const int* __restrict__ rowptr,
                                                        const int* __restrict__ esrc,
                                                        const uint2* __restrict__ h0b2,
                                                        const float4* __restrict__ als4,
                                                        const float4* __restrict__ ald4,
                                                        const float4* __restrict__ b4,
                                                        const ushort_t* __restrict__ W1p,
                                                        const float* __restrict__ as1,
                                                        const float* __restrict__ ad1,
                                                        ushort_t* __restrict__ g1b,
                                                        float* __restrict__ als1,
                                                        float* __restrict__ ald1, int N){
  __shared__ ushort_t Hs[16 * SKP2];
  __shared__ float aps[4][16], apd[4][16];
  int t = threadIdx.x;
  int lane = t & 63;
  int wave = t >> 6;
  int nbase = blockIdx.x * 16;
  int h = lane >> 4;
  float4 bb = b4[lane];
  for(int j = 0; j < 4; j++){
    int n = nbase + wave * 4 + j;
    int nl = wave * 4 + j;
    uint2 o; o.x = 0u; o.y = 0u;
    if(n < N){
      int beg = rowptr[n], end = rowptr[n + 1];
      float adh = ((const float*)(ald4 + n))[h];
      float4 acc = make_float4(0.f, 0.f, 0.f, 0.f);
      float den = 0.f;
      for(int c0 = beg; c0 < end; c0 += 16){
        int e = c0 + (lane & 15);
        int s = n; float w = 0.f;
        if(e < end){
          s = esrc[e];
          w = expf(lrelu_f(((const float*)(als4 + s))[h] + adh));
        }
        int rem = end - c0;               // wave-uniform
        if(rem > 16) rem = 16;
        #pragma unroll
        for(int g = 0; g < 4; g++){
          if(g * 4 < rem){
            int si[4]; float wi[4]; uint2 v[4];
            #pragma unroll
            for(int ii = 0; ii < 4; ii++){
              int idx = (lane & 48) + g * 4 + ii;
              si[ii] = __shfl(s, idx, 64);
              wi[ii] = __shfl(w, idx, 64);
            }
            #pragma unroll
            for(int ii = 0; ii < 4; ii++)
              v[ii] = h0b2[((size_t)si[ii] << 6) + lane];
            #pragma unroll
            for(int ii = 0; ii < 4; ii++){
              acc.x = fmaf(wi[ii], b2f_lo(v[ii].x), acc.x);
              acc.y = fmaf(wi[ii], b2f_hi(v[ii].x), acc.y);
              acc.z = fmaf(wi[ii], b2f_lo(v[ii].y), acc.z);
              acc.w = fmaf(wi[ii], b2f_hi(v[ii].y), acc.w);
              den += wi[ii];
            }
          }
        }
      }
      float inv = 1.f / (den + 1e-16f);
      float v0 = elu_f(acc.x * inv + bb.x);
      float v1 = elu_f(acc.y * inv + bb.y);
      float v2 = elu_f(acc.z * inv + bb.z);
      float v3 = elu_f(acc.w * inv + bb.w);
      o.x = (unsigned)f2b(v0) | ((unsigned)f2b(v1) << 16);
      o.y = (unsigned)f2b(v2) | ((unsigned)f2b(v3) << 16);
    }
    *(uint2*)(Hs + nl * SKP2 + lane * 4) = o;
  }
  __syncthreads();
  // ---- phase 2: g1[16x64] = h1[16x256] @ W1 (per-wave 16-col quadrant) ----
  int m = lane & 15, q = lane >> 4;
  const ushort_t* Bw = W1p + (size_t)(wave * 16 + m) * 256 + q * 8;
  const ushort_t* Aw = Hs + m * SKP2 + q * 8;
  f32x4 acc1 = {};
  #pragma unroll
  for(int k0 = 0; k0 < 256; k0 += 32){
    short8 av = *(const short8*)(Aw + k0);
    short8 bv = *(const short8*)(Bw + k0);
    acc1 = __builtin_amdgcn_mfma_f32_16x16x32_bf16(av, bv, acc1, 0, 0, 0);
  }
  #pragma unroll
  for(int i = 0; i < 4; i++){
    int gn = nbase + q * 4 + i;
    if(gn < N) g1b[(size_t)gn * 64 + wave * 16 + m] = f2b(acc1[i]);
  }
  float a_s = as1[wave * 16 + m], a_d = ad1[wave * 16 + m];
  float vs[4], vd[4];
  #pragma unroll
  for(int i = 0; i < 4; i++){
    vs[i] = acc1[i] * a_s;
    vd[i] = acc1[i] * a_d;
  }
  #pragma unroll
  for(int off = 8; off > 0; off >>= 1){
    #pragma unroll
    for(int i = 0; i < 4; i++){
      vs[i] += __shfl_down(vs[i], off, 16);
      vd[i] += __shfl_down(vd[i], off, 16);
    }
  }
  if(m == 0){
    #pragma unroll
    for(int i = 0; i < 4; i++){
      aps[wave][q * 4 + i] = vs[i];
      apd[wave][q * 4 + i] = vd[i];
    }
  }
  __syncthreads();
  if(t < 16){
    int gn = nbase + t;
    if(gn < N){
      als1[gn] = aps[0][t] + aps[1][t] + aps[2][t] + aps[3][t];
      ald1[gn] = apd[0][t] + apd[1][t] + apd[2][t] + apd[3][t];
    }
  }
}

// ---------------- agg1-L1 + GEMM2 fused --------------------------------------
// L1 agg: one node per 16-lane group (4 nodes/wave, 16 nodes/block).
#define H2S 72    // LDS h2 tile k-stride (shorts)
__global__ __launch_bounds__(256, 8) void agg1g2_kernel(const int* __restrict__ rowptr,
                                                        const int* __restrict__ esrc,
                                                        const uint2* __restrict__ g1b2,
                                                        const float* __restrict__ als1,
                                                        const float* __restrict__ ald1,
                                                        const float* __restrict__ b1,
                                                        const ushort_t* __restrict__ W2p,
                                                        const float* __restrict__ as2,
                                                        const float* __restrict__ ad2,
                                                        ushort_t* __restrict__ g2b,
                                                        float* __restrict__ als2,
                                                        float* __restrict__ ald2, int N){
  __shared__ ushort_t Hs[16 * H2S];
  __shared__ float aps[4][16], apd[4][16];
  int t = threadIdx.x;
  int wave = t >> 6, lane = t & 63;
  int nbase = blockIdx.x * 16;
  int g = lane >> 4;                 // group in wave
  int p = lane & 15;                 // lane in group
  int n = nbase + wave * 4 + g;
  int nl = wave * 4 + g;
  if(n < N){
    int beg = rowptr[n], end = rowptr[n + 1];
    float ad = ald1[n];
    float4 acc = make_float4(0.f, 0.f, 0.f, 0.f);
    float den = 0.f;
    for(int c0 = beg; c0 < end; c0 += 16){
      int e = c0 + p;
      int s = n; float w = 0.f;
      if(e < end){
        s = esrc[e];
        w = expf(lrelu_f(als1[s] + ad));
      }
      int rem = end - c0;            // group-uniform
      if(rem > 16) rem = 16;
      #pragma unroll
      for(int gg = 0; gg < 4; gg++){
        if(gg * 4 < rem){
          #pragma unroll
          for(int ii = 0; ii < 4; ii++){
            int i = gg * 4 + ii;
            int idx = (lane & 48) + i;
            int si = __shfl(s, idx, 64);
            float wi = __shfl(w, idx, 64);
            uint2 v = g1b2[((size_t)si << 4) + p];
            acc.x = fmaf(wi, b2f_lo(v.x), acc.x);
            acc.y = fmaf(wi, b2f_hi(v.x), acc.y);
            acc.z = fmaf(wi, b2f_lo(v.y), acc.z);
            acc.w = fmaf(wi, b2f_hi(v.y), acc.w);
            den += wi;
          }
        }
      }
    }
    float inv = 1.f / (den + 1e-16f);
    float4 bb = ((const float4*)b1)[p];
    unsigned o0 = (unsigned)f2b(elu_f(acc.x * inv + bb.x)) |
                  ((unsigned)f2b(elu_f(acc.y * inv + bb.y)) << 16);
    unsigned o1 = (unsigned)f2b(elu_f(acc.z * inv + bb.z)) |
                  ((unsigned)f2b(elu_f(acc.w * inv + bb.w)) << 16);
    uint2 ov; ov.x = o0; ov.y = o1;
    *(uint2*)(Hs + nl * H2S + p * 4) = ov;
  }
  __syncthreads();
  int m = lane & 15, q = lane >> 4;
  const ushort_t* Bw = W2p + (size_t)(wave * 16 + m) * 64 + q * 8;
  const ushort_t* Aw = Hs + m * H2S + q * 8;
  f32x4 acc = {};
  #pragma unroll
  for(int k0 = 0; k0 < 64; k0 += 32){
    short8 av = *(const short8*)(Aw + k0);
    short8 bv = *(const short8*)(Bw + k0);
    acc = __builtin_amdgcn_mfma_f32_16x16x32_bf16(av, bv, acc, 0, 0, 0);
  }
  float a_s = as2[wave * 16 + m], a_d = ad2[wave * 16 + m];
  float vs[4], vd[4];
  #pragma unroll
  for(int i = 0; i < 4; i++){
    int gn = nbase + q * 4 + i;
    if(gn < N) g2b[(size_t)gn * 64 + wave * 16 + m] = f2b(acc[i]);
    vs[i] = acc[i] * a_s;
    vd[i] = acc[i] * a_d;
  }
  #pragma unroll
  for(int off = 8; off > 0; off >>= 1){
    #pragma unroll
    for(int i = 0; i < 4; i++){
      vs[i] += __shfl_down(vs[i], off, 16);
      vd[i] += __shfl_down(vd[i], off, 16);
    }
  }
  if(m == 0){
    #pragma unroll
    for(int i = 0; i < 4; i++){
      aps[wave][q * 4 + i] = vs[i];
      apd[wave][q * 4 + i] = vd[i];
    }
  }
  __syncthreads();
  if(t < 16){
    int gn = nbase + t;
    if(gn < N){
      als2[gn] = aps[0][t] + aps[1][t] + aps[2][t] + aps[3][t];
      ald2[gn] = apd[0][t] + apd[1][t] + apd[2][t] + apd[3][t];
    }
  }
}

// ---------------- final agg (layer 2): 16-lane group per node, fp32 out ------
__global__ __launch_bounds__(256, 8) void aggF_kernel(const int* __restrict__ rowptr,
                                                      const int* __restrict__ esrc,
                                                      const uint2* __restrict__ gb2,
                                                      const float* __restrict__ als,
                                                      const float* __restrict__ ald,
                                                      const float* __restrict__ b,
                                                      float4* __restrict__ outp, int N){
  int t = threadIdx.x;
  int lane = t & 63;
  int g = lane >> 4;
  int p = lane & 15;
  int n = blockIdx.x * 16 + (t >> 6) * 4 + g;
  if(n >= N) return;
  int beg = rowptr[n], end = rowptr[n + 1];
  float ad = ald[n];
  float4 acc = make_float4(0.f, 0.f, 0.f, 0.f);
  float den = 0.f;
  for(int c0 = beg; c0 < end; c0 += 16){
    int e = c0 + p;
    int s = n; float w = 0.f;
    if(e < end){
      s = esrc[e];
      w = expf(lrelu_f(als[s] + ad));
    }
    int rem = end - c0;              // group-uniform
    if(rem > 16) rem = 16;
    #pragma unroll
    for(int gg = 0; gg < 4; gg++){
      if(gg * 4 < rem){
        #pragma unroll
        for(int ii = 0; ii < 4; ii++){
          int i = gg * 4 + ii;
          int idx = (lane & 48) + i;
          int si = __shfl(s, idx, 64);
          float wi = __shfl(w, idx, 64);
          uint2 v = gb2[((size_t)si << 4) + p];
          acc.x = fmaf(wi, b2f_lo(v.x), acc.x);
          acc.y = fmaf(wi, b2f_hi(v.x), acc.y);
          acc.z = fmaf(wi, b2f_lo(v.y), acc.z);
          acc.w = fmaf(wi, b2f_hi(v.y), acc.w);
          den += wi;
        }
      }
    }
  }
  float inv = 1.f / (den + 1e-16f);
  float4 bb = ((const float4*)b)[p];
  float4 o;
  o.x = elu_f(acc.x * inv + bb.x);
  o.y = elu_f(acc.y * inv + bb.y);
  o.z = elu_f(acc.z * inv + bb.z);
  o.w = elu_f(acc.w * inv + bb.w);
  outp[((size_t)n << 4) + p] = o;
}

extern "C" void kernel_launch(void* const* d_in, const int* in_sizes, int n_in,
                              void* d_out, int out_size, void* d_ws, size_t ws_size,
                              hipStream_t stream){
  const float* x   = (const float*)d_in[0];
  const int*   ei  = (const int*)d_in[1];
  const float* W0  = (const float*)d_in[2];
  const float* as0 = (const float*)d_in[3];
  const float* ad0 = (const float*)d_in[4];
  const float* b0  = (const float*)d_in[5];
  const float* W1  = (const float*)d_in[6];
  const float* as1 = (const float*)d_in[7];
  const float* ad1 = (const float*)d_in[8];
  const float* b1  = (const float*)d_in[9];
  const float* W2  = (const float*)d_in[10];
  const float* as2 = (const float*)d_in[11];
  const float* ad2 = (const float*)d_in[12];
  const float* b2  = (const float*)d_in[13];
  int N = in_sizes[0] / 256;
  int E = in_sizes[1] / 2;
  int Etot = E + N;

  size_t off = 0;
  auto alc = [&](size_t bytes) -> char* {
    char* p = (char*)d_ws + off;
    off += (bytes + 255) & ~(size_t)255;
    return p;
  };
  ushort_t* xb    = (ushort_t*)alc((size_t)N * 256 * 2); // x bf16; g1b aliases
  ushort_t* h0b   = (ushort_t*)alc((size_t)N * 256 * 2); // h0 bf16; g2b aliases
  float*    als   = (float*)alc((size_t)N * 4 * 4);
  float*    ald   = (float*)alc((size_t)N * 4 * 4);
  float*    als1  = (float*)alc((size_t)N * 4);
  float*    ald1  = (float*)alc((size_t)N * 4);
  float*    als2  = (float*)alc((size_t)N * 4);
  float*    ald2  = (float*)alc((size_t)N * 4);
  int*      esrc  = (int*)alc((size_t)Etot * 4);
  int*      rowptr= (int*)alc((size_t)(N + 1) * 4);
  int*      cnt   = (int*)alc((size_t)N * 4);
  int*      cursor= (int*)alc((size_t)N * 4);
  int*      bsum  = (int*)alc(256 * 4);
  ushort_t* W0p   = (ushort_t*)alc(256 * 256 * 2);
  ushort_t* W1p   = (ushort_t*)alc(256 * 64 * 2);
  ushort_t* W2p   = (ushort_t*)alc(64 * 64 * 2);

  ushort_t* g1b = xb;                      // xb dead after gemm0
  ushort_t* g2b = h0b;                     // h0b dead after agg0g1

  int nb = (N + 255) / 256;                // <= 256 chunks
  int eb = (Etot + 255) / 256;
  int fb = (N * 64 + 255) / 256;
  int g0b = (N + 31) / 32;
  int tb = (N + 15) / 16;
  int ab16 = (N + 15) / 16;

  // ---- prep + CSR build ----
  hipMemsetAsync(cnt, 0, (size_t)N * 4, stream);
  prep_kernel<<<eb + fb + 336, 256, 0, stream>>>(ei, cnt, (const float4*)x,
                                                 (ushort4*)xb, N * 64,
                                                 W0, W0p, W1, W1p, W2, W2p,
                                                 E, Etot, eb, fb);
  blocksum_kernel<<<nb, 256, 0, stream>>>(cnt, bsum, N);
  scan2_kernel<<<nb, 256, 0, stream>>>(cnt, bsum, rowptr, cursor, N, Etot, nb);
  scatter_kernel<<<eb, 256, 0, stream>>>(ei, cursor, esrc, E, Etot);

  // ---- Layer 0 GEMM ----
  gemm0_kernel<<<g0b, 256, 0, stream>>>(xb, W0p, h0b, as0, ad0, als, ald, N);

  // ---- Layer 0 agg + Layer 1 GEMM (fused, 16 nodes/block) ----
  agg0g1_kernel<<<ab16, 256, 0, stream>>>(rowptr, esrc, (const uint2*)h0b,
                                          (const float4*)als, (const float4*)ald,
                                          (const float4*)b0, W1p, as1, ad1,
                                          g1b, als1, ald1, N);

  // ---- Layer 1 agg + Layer 2 GEMM (fused) ----
  agg1g2_kernel<<<tb, 256, 0, stream>>>(rowptr, esrc, (const uint2*)g1b,
                                        als1, ald1, b1, W2p, as2, ad2,
                                        g2b, als2, ald2, N);

  // ---- Layer 2 agg -> output ----
  aggF_kernel<<<ab16, 256, 0, stream>>>(rowptr, esrc, (const uint2*)g2b,
                                        als2, ald2, b2, (float4*)d_out, N);
}

// Round 8
// 359.677 us; speedup vs baseline: 1.0572x; 1.0009x over previous
//
#include <hip/hip_runtime.h>
#include <hip/hip_bf16.h>

// ModifiedGAT, round 19:
//  - r18 post-mortem: CLT batching fixed the convoy as predicted (104->79.7us,
//    total 360 = best). Two further cuts:
//  (1) xb round-trip DELETED: gemm0 stages x fp32 directly (float4x2 -> f2b
//      during LDS fill); prep loses its 12500-block conversion section.
//      Net -51MB pipeline traffic. Bit-identical (same f2b, applied later).
//  (2) agg0g1 at 32 nodes/block (wave gathers 8 sequential nodes): convoy
//      util 0.89->0.93, W1p slice reused 2x, LDS 17.9KB (8 blocks/CU = 143KB).
//  - Pipeline: memset | prep | blocksum | scan2 | scatter | gemm0 | agg0g1 |
//              agg1g2 | aggF  (9 dispatches).

typedef unsigned short ushort_t;
typedef __attribute__((ext_vector_type(8))) short short8;
typedef __attribute__((ext_vector_type(4))) float f32x4;

__device__ __forceinline__ float elu_f(float x){ return x > 0.f ? x : expm1f(x); }
__device__ __forceinline__ float lrelu_f(float x){ return x > 0.f ? x : 0.2f * x; }
__device__ __forceinline__ ushort_t f2b(float f){
  union { float f; unsigned u; } v; v.f = f;
  unsigned r = v.u + 0x7fff + ((v.u >> 16) & 1);   // round-to-nearest-even
  return (ushort_t)(r >> 16);
}
__device__ __forceinline__ float b2f_lo(unsigned v){
  union { unsigned u; float f; } c; c.u = v << 16; return c.f;
}
__device__ __forceinline__ float b2f_hi(unsigned v){
  union { unsigned u; float f; } c; c.u = v & 0xffff0000u; return c.f;
}

// ---------------- prep: hist + weight transposes (x conversion removed) ------
__global__ __launch_bounds__(256) void prep_kernel(const int* __restrict__ ei,
                                                   int* __restrict__ cnt,
                                                   const float* __restrict__ W0,
                                                   ushort_t* __restrict__ W0p,
                                                   const float* __restrict__ W1,
                                                   ushort_t* __restrict__ W1p,
                                                   const float* __restrict__ W2,
                                                   ushort_t* __restrict__ W2p,
                                                   int E, int Etot, int eb){
  int bid = blockIdx.x; int t = threadIdx.x;
  if(bid < eb){
    int e = bid * 256 + t;
    if(e < Etot){
      int d = (e < E) ? ei[E + e] : (e - E);
      atomicAdd(&cnt[d], 1);
    }
  } else {
    int r = bid - eb;
    if(r < 256){            // W0: 256x256
      int i = r * 256 + t; int k = i >> 8, n = i & 255;
      W0p[(size_t)n * 256 + k] = f2b(W0[i]);
    } else if(r < 320){     // W1: 256x64
      int i = (r - 256) * 256 + t; int k = i >> 6, n = i & 63;
      W1p[(size_t)n * 256 + k] = f2b(W1[i]);
    } else {                // W2: 64x64
      int i = (r - 320) * 256 + t; int k = i >> 6, n = i & 63;
      W2p[(size_t)n * 64 + k] = f2b(W2[i]);
    }
  }
}

// ---------------- CSR scan -----------------------------------------------------
__global__ __launch_bounds__(256) void blocksum_kernel(const int* __restrict__ cnt,
                                                       int* __restrict__ bsum, int N){
  __shared__ int sm[256];
  int t = threadIdx.x;
  int i = blockIdx.x * 256 + t;
  sm[t] = (i < N) ? cnt[i] : 0;
  __syncthreads();
  for(int off = 128; off > 0; off >>= 1){
    if(t < off) sm[t] += sm[t + off];
    __syncthreads();
  }
  if(t == 0) bsum[blockIdx.x] = sm[0];
}

// scan2 with internal bsum prefix (scanb folded in); nb <= 256.
__global__ __launch_bounds__(256) void scan2_kernel(const int* __restrict__ cnt,
                                                    const int* __restrict__ bsum,
                                                    int* __restrict__ rowptr,
                                                    int* __restrict__ cursor,
                                                    int N, int Etot, int nb){
  __shared__ int sm[256];
  __shared__ int spfx;
  int t = threadIdx.x;
  int c = blockIdx.x;
  // prefix = sum of bsum[0..c)
  sm[t] = (t < c && t < nb) ? bsum[t] : 0;
  __syncthreads();
  for(int off = 128; off > 0; off >>= 1){
    if(t < off) sm[t] += sm[t + off];
    __syncthreads();
  }
  if(t == 0) spfx = sm[0];
  __syncthreads();
  int pfx = spfx;
  __syncthreads();
  // chunk-local exclusive scan
  int i = c * 256 + t;
  int v = (i < N) ? cnt[i] : 0;
  sm[t] = v;
  __syncthreads();
  for(int off = 1; off < 256; off <<= 1){
    int x = 0;
    if(t >= off) x = sm[t - off];
    __syncthreads();
    sm[t] += x;
    __syncthreads();
  }
  if(i < N){
    int ex = sm[t] - v + pfx;
    rowptr[i] = ex;
    cursor[i] = ex;
    if(i == N - 1) rowptr[N] = Etot;
  }
}

__global__ __launch_bounds__(256) void scatter_kernel(const int* __restrict__ ei,
                                                      int* __restrict__ cursor,
                                                      int* __restrict__ esrc,
                                                      int E, int Etot){
  int e = blockIdx.x * 256 + threadIdx.x;
  if(e >= Etot) return;
  int s, d;
  if(e < E){ s = ei[e]; d = ei[E + e]; } else { s = e - E; d = s; }
  int pos = atomicAdd(&cursor[d], 1);
  esrc[pos] = s;
}

// ---------------- GEMM0: h0b[M,256] = bf16(x[M,256] @ W0) + logits ----------
// A staged directly from fp32 x (f2b during LDS fill) — no xb round-trip.
#define SKP 264   // padded LDS k-stride (shorts)
__global__ __launch_bounds__(256) void gemm0_kernel(const float4* __restrict__ x4,
                                                    const ushort_t* __restrict__ Bp,
                                                    ushort_t* __restrict__ h0b,
                                                    const float* __restrict__ asrc,
                                                    const float* __restrict__ adst,
                                                    float* __restrict__ als,
                                                    float* __restrict__ ald, int M){
  __shared__ ushort_t As[32 * SKP];
  int t = threadIdx.x;
  int row0 = blockIdx.x * 32;
  {
    int c = t;
    #pragma unroll
    for(int it = 0; it < 4; it++, c += 256){
      int r = c >> 5;
      int kc = (c & 31) << 3;          // col in shorts (multiple of 8)
      int gr = row0 + r;
      short8 v = {};
      if(gr < M){
        float4 f0 = x4[(size_t)gr * 64 + (kc >> 2)];
        float4 f1 = x4[(size_t)gr * 64 + (kc >> 2) + 1];
        v[0] = (short)f2b(f0.x); v[1] = (short)f2b(f0.y);
        v[2] = (short)f2b(f0.z); v[3] = (short)f2b(f0.w);
        v[4] = (short)f2b(f1.x); v[5] = (short)f2b(f1.y);
        v[6] = (short)f2b(f1.z); v[7] = (short)f2b(f1.w);
      }
      *(short8*)(As + r * SKP + kc) = v;
    }
  }
  __syncthreads();
  int wave = t >> 6, lane = t & 63;
  int m = lane & 15, q = lane >> 4;
  int colb = wave;                   // head
  const ushort_t* Bq = Bp + (size_t)(colb * 64 + m) * 256 + q * 8;
  const ushort_t* A0 = As + m * SKP + q * 8;
  const ushort_t* A1 = As + (16 + m) * SKP + q * 8;
  f32x4 acc[2][4] = {};
  for(int k0 = 0; k0 < 256; k0 += 32){
    short8 bv[4];
    #pragma unroll
    for(int j = 0; j < 4; j++) bv[j] = *(const short8*)(Bq + (size_t)j * 16 * 256 + k0);
    short8 a0 = *(const short8*)(A0 + k0);
    short8 a1 = *(const short8*)(A1 + k0);
    #pragma unroll
    for(int j = 0; j < 4; j++){
      acc[0][j] = __builtin_amdgcn_mfma_f32_16x16x32_bf16(a0, bv[j], acc[0][j], 0, 0, 0);
      acc[1][j] = __builtin_amdgcn_mfma_f32_16x16x32_bf16(a1, bv[j], acc[1][j], 0, 0, 0);
    }
  }
  #pragma unroll
  for(int rt = 0; rt < 2; rt++){
    #pragma unroll
    for(int j = 0; j < 4; j++){
      int col = colb * 64 + j * 16 + m;
      #pragma unroll
      for(int i = 0; i < 4; i++){
        int gr = row0 + rt * 16 + q * 4 + i;
        if(gr < M) h0b[(size_t)gr * 256 + col] = f2b(acc[rt][j][i]);
      }
    }
    float vs[4] = {0,0,0,0}, vd[4] = {0,0,0,0};
    #pragma unroll
    for(int j = 0; j < 4; j++){
      int col = colb * 64 + j * 16 + m;
      float a_s = asrc[col], a_d = adst[col];
      #pragma unroll
      for(int i = 0; i < 4; i++){
        vs[i] = fmaf(acc[rt][j][i], a_s, vs[i]);
        vd[i] = fmaf(acc[rt][j][i], a_d, vd[i]);
      }
    }
    #pragma unroll
    for(int off = 8; off > 0; off >>= 1){
      #pragma unroll
      for(int i = 0; i < 4; i++){
        vs[i] += __shfl_down(vs[i], off, 16);
        vd[i] += __shfl_down(vd[i], off, 16);
      }
    }
    if(m == 0){
      #pragma unroll
      for(int i = 0; i < 4; i++){
        int gr = row0 + rt * 16 + q * 4 + i;
        if(gr < M){
          als[(size_t)gr * 4 + colb] = vs[i];
          ald[(size_t)gr * 4 + colb] = vd[i];
        }
      }
    }
  }
}

// ---------------- agg0 + GEMM1 fused (32 nodes/block) ------------------------
// Phase 1: wave w gathers nodes nbase+w*8..w*8+7 sequentially; h1 rows -> LDS.
// Phase 2: two 16-row A tiles; wave w computes cols w*16..15 for both tiles
//          (16 MFMA); emits g1b + layer-1 logits.
#define SKP2 264
__global__ __launch_bounds__(256, 8) void agg0g1_kernel(const int* __restrict__ rowptr,
                                                        const int* __restrict__ esrc,
                                                        const uint2* __restrict__ h0b2,
                                                        const float4* __restrict__ als4,
                                                        const float4* __restrict__ ald4,
                                                        const float4* __restrict__ b4,
                                                        const ushort_t* __restrict__ W1p,
                                                        const float* __restrict__ as1,
                                                        const float* __restrict__ ad1,
                                                        ushort_t* __restrict__ g1b,
                                                        float* __restrict__ als1,
                                                        float* __restrict__ ald1, int N){
  __shared__ ushort_t Hs[32 * SKP2];
  __shared__ float aps[4][32], apd[4][32];
  int t = threadIdx.x;
  int lane = t & 63;
  int wave = t >> 6;
  int nbase = blockIdx.x * 32;
  int h = lane >> 4;
  float4 bb = b4[lane];
  for(int j = 0; j < 8; j++){
    int n = nbase + wave * 8 + j;
    int nl = wave * 8 + j;
    uint2 o; o.x = 0u; o.y = 0u;
    if(n < N){
      int beg = rowptr[n], end = rowptr[n + 1];
      float adh = ((const float*)(ald4 + n))[h];
      float4 acc = make_float4(0.f, 0.f, 0.f, 0.f);
      float den = 0.f;
      for(int c0 = beg; c0 < end; c0 += 16){
        int e = c0 + (lane & 15);
        int s = n; float w = 0.f;
        if(e < end){
          s = esrc[e];
          w = expf(lrelu_f(((const float*)(als4 + s))[h] + adh));
        }
        int rem = end - c0;               // wave-uniform
        if(rem > 16) rem = 16;
        #pragma unroll
        for(int g = 0; g < 4; g++){
          if(g * 4 < rem){
            int si[4]; float wi[4]; uint2 v[4];
            #pragma unroll
            for(int ii = 0; ii < 4; ii++){
              int idx = (lane & 48) + g * 4 + ii;
              si[ii] = __shfl(s, idx, 64);
              wi[ii] = __shfl(w, idx, 64);
            }
            #pragma unroll
            for(int ii = 0; ii < 4; ii++)
              v[ii] = h0b2[((size_t)si[ii] << 6) + lane];
            #pragma unroll
            for(int ii = 0; ii < 4; ii++){
              acc.x = fmaf(wi[ii], b2f_lo(v[ii].x), acc.x);
              acc.y = fmaf(wi[ii], b2f_hi(v[ii].x), acc.y);
              acc.z = fmaf(wi[ii], b2f_lo(v[ii].y), acc.z);
              acc.w = fmaf(wi[ii], b2f_hi(v[ii].y), acc.w);
              den += wi[ii];
            }
          }
        }
      }
      float inv = 1.f / (den + 1e-16f);
      float v0 = elu_f(acc.x * inv + bb.x);
      float v1 = elu_f(acc.y * inv + bb.y);
      float v2 = elu_f(acc.z * inv + bb.z);
      float v3 = elu_f(acc.w * inv + bb.w);
      o.x = (unsigned)f2b(v0) | ((unsigned)f2b(v1) << 16);
      o.y = (unsigned)f2b(v2) | ((unsigned)f2b(v3) << 16);
    }
    *(uint2*)(Hs + nl * SKP2 + lane * 4) = o;
  }
  __syncthreads();
  // ---- phase 2: g1[32x64] = h1[32x256] @ W1 (per-wave 16-col quadrant) ----
  int m = lane & 15, q = lane >> 4;
  const ushort_t* Bw = W1p + (size_t)(wave * 16 + m) * 256 + q * 8;
  float a_s = as1[wave * 16 + m], a_d = ad1[wave * 16 + m];
  #pragma unroll
  for(int rt = 0; rt < 2; rt++){
    const ushort_t* Aw = Hs + (rt * 16 + m) * SKP2 + q * 8;
    f32x4 acc1 = {};
    #pragma unroll
    for(int k0 = 0; k0 < 256; k0 += 32){
      short8 av = *(const short8*)(Aw + k0);
      short8 bv = *(const short8*)(Bw + k0);
      acc1 = __builtin_amdgcn_mfma_f32_16x16x32_bf16(av, bv, acc1, 0, 0, 0);
    }
    #pragma unroll
    for(int i = 0; i < 4; i++){
      int gn = nbase + rt * 16 + q * 4 + i;
      if(gn < N) g1b[(size_t)gn * 64 + wave * 16 + m] = f2b(acc1[i]);
    }
    float vs[4], vd[4];
    #pragma unroll
    for(int i = 0; i < 4; i++){
      vs[i] = acc1[i] * a_s;
      vd[i] = acc1[i] * a_d;
    }
    #pragma unroll
    for(int off = 8; off > 0; off >>= 1){
      #pragma unroll
      for(int i = 0; i < 4; i++){
        vs[i] += __shfl_down(vs[i], off, 16);
        vd[i] += __shfl_down(vd[i], off, 16);
      }
    }
    if(m == 0){
      #pragma unroll
      for(int i = 0; i < 4; i++){
        aps[wave][rt * 16 + q * 4 + i] = vs[i];
        apd[wave][rt * 16 + q * 4 + i] = vd[i];
      }
    }
  }
  __syncthreads();
  if(t < 32){
    int gn = nbase + t;
    if(gn < N){
      als1[gn] = aps[0][t] + aps[1][t] + aps[2][t] + aps[3][t];
      ald1[gn] = apd[0][t] + apd[1][t] + apd[2][t] + apd[3][t];
    }
  }
}

// ---------------- agg1-L1 + GEMM2 fused --------------------------------------
// L1 agg: one node per 16-lane group (4 nodes/wave, 16 nodes/block).
#define H2S 72    // LDS h2 tile k-stride (shorts)
__global__ __launch_bounds__(256, 8) void agg1g2_kernel(const int* __restrict__ rowptr,
                                                        const int* __restrict__ esrc,
                                                        const uint2* __restrict__ g1b2,
                                                        const float* __restrict__ als1,
                                                        const float* __restrict__ ald1,
                                                        const float* __restrict__ b1,
                                                        const ushort_t* __restrict__ W2p,
                                                        const float* __restrict__ as2,
                                                        const float* __restrict__ ad2,
                                                        ushort_t* __restrict__ g2b,
                                                        float* __restrict__ als2,
                                                        float* __restrict__ ald2, int N){
  __shared__ ushort_t Hs[16 * H2S];
  __shared__ float aps[4][16], apd[4][16];
  int t = threadIdx.x;
  int wave = t >> 6, lane = t & 63;
  int nbase = blockIdx.x * 16;
  int g = lane >> 4;                 // group in wave
  int p = lane & 15;                 // lane in group
  int n = nbase + wave * 4 + g;
  int nl = wave * 4 + g;
  if(n < N){
    int beg = rowptr[n], end = rowptr[n + 1];
    float ad = ald1[n];
    float4 acc = make_float4(0.f, 0.f, 0.f, 0.f);
    float den = 0.f;
    for(int c0 = beg; c0 < end; c0 += 16){
      int e = c0 + p;
      int s = n; float w = 0.f;
      if(e < end){
        s = esrc[e];
        w = expf(lrelu_f(als1[s] + ad));
      }
      int rem = end - c0;            // group-uniform
      if(rem > 16) rem = 16;
      #pragma unroll
      for(int gg = 0; gg < 4; gg++){
        if(gg * 4 < rem){
          #pragma unroll
          for(int ii = 0; ii < 4; ii++){
            int i = gg * 4 + ii;
            int idx = (lane & 48) + i;
            int si = __shfl(s, idx, 64);
            float wi = __shfl(w, idx, 64);
            uint2 v = g1b2[((size_t)si << 4) + p];
            acc.x = fmaf(wi, b2f_lo(v.x), acc.x);
            acc.y = fmaf(wi, b2f_hi(v.x), acc.y);
            acc.z = fmaf(wi, b2f_lo(v.y), acc.z);
            acc.w = fmaf(wi, b2f_hi(v.y), acc.w);
            den += wi;
          }
        }
      }
    }
    float inv = 1.f / (den + 1e-16f);
    float4 bb = ((const float4*)b1)[p];
    unsigned o0 = (unsigned)f2b(elu_f(acc.x * inv + bb.x)) |
                  ((unsigned)f2b(elu_f(acc.y * inv + bb.y)) << 16);
    unsigned o1 = (unsigned)f2b(elu_f(acc.z * inv + bb.z)) |
                  ((unsigned)f2b(elu_f(acc.w * inv + bb.w)) << 16);
    uint2 ov; ov.x = o0; ov.y = o1;
    *(uint2*)(Hs + nl * H2S + p * 4) = ov;
  }
  __syncthreads();
  int m = lane & 15, q = lane >> 4;
  const ushort_t* Bw = W2p + (size_t)(wave * 16 + m) * 64 + q * 8;
  const ushort_t* Aw = Hs + m * H2S + q * 8;
  f32x4 acc = {};
  #pragma unroll
  for(int k0 = 0; k0 < 64; k0 += 32){
    short8 av = *(const short8*)(Aw + k0);
    short8 bv = *(const short8*)(Bw + k0);
    acc = __builtin_amdgcn_mfma_f32_16x16x32_bf16(av, bv, acc, 0, 0, 0);
  }
  float a_s = as2[wave * 16 + m], a_d = ad2[wave * 16 + m];
  float vs[4], vd[4];
  #pragma unroll
  for(int i = 0; i < 4; i++){
    int gn = nbase + q * 4 + i;
    if(gn < N) g2b[(size_t)gn * 64 + wave * 16 + m] = f2b(acc[i]);
    vs[i] = acc[i] * a_s;
    vd[i] = acc[i] * a_d;
  }
  #pragma unroll
  for(int off = 8; off > 0; off >>= 1){
    #pragma unroll
    for(int i = 0; i < 4; i++){
      vs[i] += __shfl_down(vs[i], off, 16);
      vd[i] += __shfl_down(vd[i], off, 16);
    }
  }
  if(m == 0){
    #pragma unroll
    for(int i = 0; i < 4; i++){
      aps[wave][q * 4 + i] = vs[i];
      apd[wave][q * 4 + i] = vd[i];
    }
  }
  __syncthreads();
  if(t < 16){
    int gn = nbase + t;
    if(gn < N){
      als2[gn] = aps[0][t] + aps[1][t] + aps[2][t] + aps[3][t];
      ald2[gn] = apd[0][t] + apd[1][t] + apd[2][t] + apd[3][t];
    }
  }
}

// ---------------- final agg (layer 2): 16-lane group per node, fp32 out ------
__global__ __launch_bounds__(256, 8) void aggF_kernel(const int* __restrict__ rowptr,
                                                      const int* __restrict__ esrc,
                                                      const uint2* __restrict__ gb2,
                                                      const float* __restrict__ als,
                                                      const float* __restrict__ ald,
                                                      const float* __restrict__ b,
                                                      float4* __restrict__ outp, int N){
  int t = threadIdx.x;
  int lane = t & 63;
  int g = lane >> 4;
  int p = lane & 15;
  int n = blockIdx.x * 16 + (t >> 6) * 4 + g;
  if(n >= N) return;
  int beg = rowptr[n], end = rowptr[n + 1];
  float ad = ald[n];
  float4 acc = make_float4(0.f, 0.f, 0.f, 0.f);
  float den = 0.f;
  for(int c0 = beg; c0 < end; c0 += 16){
    int e = c0 + p;
    int s = n; float w = 0.f;
    if(e < end){
      s = esrc[e];
      w = expf(lrelu_f(als[s] + ad));
    }
    int rem = end - c0;              // group-uniform
    if(rem > 16) rem = 16;
    #pragma unroll
    for(int gg = 0; gg < 4; gg++){
      if(gg * 4 < rem){
        #pragma unroll
        for(int ii = 0; ii < 4; ii++){
          int i = gg * 4 + ii;
          int idx = (lane & 48) + i;
          int si = __shfl(s, idx, 64);
          float wi = __shfl(w, idx, 64);
          uint2 v = gb2[((size_t)si << 4) + p];
          acc.x = fmaf(wi, b2f_lo(v.x), acc.x);
          acc.y = fmaf(wi, b2f_hi(v.x), acc.y);
          acc.z = fmaf(wi, b2f_lo(v.y), acc.z);
          acc.w = fmaf(wi, b2f_hi(v.y), acc.w);
          den += wi;
        }
      }
    }
  }
  float inv = 1.f / (den + 1e-16f);
  float4 bb = ((const float4*)b)[p];
  float4 o;
  o.x = elu_f(acc.x * inv + bb.x);
  o.y = elu_f(acc.y * inv + bb.y);
  o.z = elu_f(acc.z * inv + bb.z);
  o.w = elu_f(acc.w * inv + bb.w);
  outp[((size_t)n << 4) + p] = o;
}

extern "C" void kernel_launch(void* const* d_in, const int* in_sizes, int n_in,
                              void* d_out, int out_size, void* d_ws, size_t ws_size,
                              hipStream_t stream){
  const float* x   = (const float*)d_in[0];
  const int*   ei  = (const int*)d_in[1];
  const float* W0  = (const float*)d_in[2];
  const float* as0 = (const float*)d_in[3];
  const float* ad0 = (const float*)d_in[4];
  const float* b0  = (const float*)d_in[5];
  const float* W1  = (const float*)d_in[6];
  const float* as1 = (const float*)d_in[7];
  const float* ad1 = (const float*)d_in[8];
  const float* b1  = (const float*)d_in[9];
  const float* W2  = (const float*)d_in[10];
  const float* as2 = (const float*)d_in[11];
  const float* ad2 = (const float*)d_in[12];
  const float* b2  = (const float*)d_in[13];
  int N = in_sizes[0] / 256;
  int E = in_sizes[1] / 2;
  int Etot = E + N;

  size_t off = 0;
  auto alc = [&](size_t bytes) -> char* {
    char* p = (char*)d_ws + off;
    off += (bytes + 255) & ~(size_t)255;
    return p;
  };
  ushort_t* g1b   = (ushort_t*)alc((size_t)N * 64 * 2);  // layer-1 gemm out
  ushort_t* h0b   = (ushort_t*)alc((size_t)N * 256 * 2); // h0 bf16; g2b aliases
  float*    als   = (float*)alc((size_t)N * 4 * 4);
  float*    ald   = (float*)alc((size_t)N * 4 * 4);
  float*    als1  = (float*)alc((size_t)N * 4);
  float*    ald1  = (float*)alc((size_t)N * 4);
  float*    als2  = (float*)alc((size_t)N * 4);
  float*    ald2  = (float*)alc((size_t)N * 4);
  int*      esrc  = (int*)alc((size_t)Etot * 4);
  int*      rowptr= (int*)alc((size_t)(N + 1) * 4);
  int*      cnt   = (int*)alc((size_t)N * 4);
  int*      cursor= (int*)alc((size_t)N * 4);
  int*      bsum  = (int*)alc(256 * 4);
  ushort_t* W0p   = (ushort_t*)alc(256 * 256 * 2);
  ushort_t* W1p   = (ushort_t*)alc(256 * 64 * 2);
  ushort_t* W2p   = (ushort_t*)alc(64 * 64 * 2);

  ushort_t* g2b = h0b;                     // h0b dead after agg0g1

  int nb = (N + 255) / 256;                // <= 256 chunks
  int eb = (Etot + 255) / 256;
  int g0b = (N + 31) / 32;
  int tb = (N + 15) / 16;
  int ab32 = (N + 31) / 32;
  int ab16 = (N + 15) / 16;

  // ---- prep + CSR build ----
  hipMemsetAsync(cnt, 0, (size_t)N * 4, stream);
  prep_kernel<<<eb + 336, 256, 0, stream>>>(ei, cnt, W0, W0p, W1, W1p, W2, W2p,
                                            E, Etot, eb);
  blocksum_kernel<<<nb, 256, 0, stream>>>(cnt, bsum, N);
  scan2_kernel<<<nb, 256, 0, stream>>>(cnt, bsum, rowptr, cursor, N, Etot, nb);
  scatter_kernel<<<eb, 256, 0, stream>>>(ei, cursor, esrc, E, Etot);

  // ---- Layer 0 GEMM (reads x fp32 directly) ----
  gemm0_kernel<<<g0b, 256, 0, stream>>>((const float4*)x, W0p, h0b,
                                        as0, ad0, als, ald, N);

  // ---- Layer 0 agg + Layer 1 GEMM (fused, 32 nodes/block) ----
  agg0g1_kernel<<<ab32, 256, 0, stream>>>(rowptr, esrc, (const uint2*)h0b,
                                          (const float4*)als, (const float4*)ald,
                                          (const float4*)b0, W1p, as1, ad1,
                                          g1b, als1, ald1, N);

  // ---- Layer 1 agg + Layer 2 GEMM (fused) ----
  agg1g2_kernel<<<tb, 256, 0, stream>>>(rowptr, esrc, (const uint2*)g1b,
                                        als1, ald1, b1, W2p, as2, ad2,
                                        g2b, als2, ald2, N);

  // ---- Layer 2 agg -> output ----
  aggF_kernel<<<ab16, 256, 0, stream>>>(rowptr, esrc, (const uint2*)g2b,
                                        als2, ald2, b2, (float4*)d_out, N);
}

// Round 9
// 355.011 us; speedup vs baseline: 1.0711x; 1.0131x over previous
//
#include <hip/hip_runtime.h>
#include <hip/hip_bf16.h>

// ModifiedGAT, round 20:
//  - r19 post-mortem: (1) xb-deletion netted +4us (kept); (2) 32-node agg0g1
//    REGRESSED 79.7->83.2us: grid shrank to 1563 blocks = 6.1/CU < 8-resident
//    => occupancy 64->52%, tail imbalance swamped the CLT gain. REVERTED to
//    r18 geometry: 16 nodes/block (3125 blocks = 12.2/CU), wave gathers 4
//    sequential nodes, phase-2 = one 16x256 A tile (8 MFMA), aps[4][16].
//  - Pipeline: memset | prep | blocksum | scan2 | scatter | gemm0 | agg0g1 |
//              agg1g2 | aggF  (9 dispatches).

typedef unsigned short ushort_t;
typedef __attribute__((ext_vector_type(8))) short short8;
typedef __attribute__((ext_vector_type(4))) float f32x4;

__device__ __forceinline__ float elu_f(float x){ return x > 0.f ? x : expm1f(x); }
__device__ __forceinline__ float lrelu_f(float x){ return x > 0.f ? x : 0.2f * x; }
__device__ __forceinline__ ushort_t f2b(float f){
  union { float f; unsigned u; } v; v.f = f;
  unsigned r = v.u + 0x7fff + ((v.u >> 16) & 1);   // round-to-nearest-even
  return (ushort_t)(r >> 16);
}
__device__ __forceinline__ float b2f_lo(unsigned v){
  union { unsigned u; float f; } c; c.u = v << 16; return c.f;
}
__device__ __forceinline__ float b2f_hi(unsigned v){
  union { unsigned u; float f; } c; c.u = v & 0xffff0000u; return c.f;
}

// ---------------- prep: hist + weight transposes (x conversion removed) ------
__global__ __launch_bounds__(256) void prep_kernel(const int* __restrict__ ei,
                                                   int* __restrict__ cnt,
                                                   const float* __restrict__ W0,
                                                   ushort_t* __restrict__ W0p,
                                                   const float* __restrict__ W1,
                                                   ushort_t* __restrict__ W1p,
                                                   const float* __restrict__ W2,
                                                   ushort_t* __restrict__ W2p,
                                                   int E, int Etot, int eb){
  int bid = blockIdx.x; int t = threadIdx.x;
  if(bid < eb){
    int e = bid * 256 + t;
    if(e < Etot){
      int d = (e < E) ? ei[E + e] : (e - E);
      atomicAdd(&cnt[d], 1);
    }
  } else {
    int r = bid - eb;
    if(r < 256){            // W0: 256x256
      int i = r * 256 + t; int k = i >> 8, n = i & 255;
      W0p[(size_t)n * 256 + k] = f2b(W0[i]);
    } else if(r < 320){     // W1: 256x64
      int i = (r - 256) * 256 + t; int k = i >> 6, n = i & 63;
      W1p[(size_t)n * 256 + k] = f2b(W1[i]);
    } else {                // W2: 64x64
      int i = (r - 320) * 256 + t; int k = i >> 6, n = i & 63;
      W2p[(size_t)n * 64 + k] = f2b(W2[i]);
    }
  }
}

// ---------------- CSR scan -----------------------------------------------------
__global__ __launch_bounds__(256) void blocksum_kernel(const int* __restrict__ cnt,
                                                       int* __restrict__ bsum, int N){
  __shared__ int sm[256];
  int t = threadIdx.x;
  int i = blockIdx.x * 256 + t;
  sm[t] = (i < N) ? cnt[i] : 0;
  __syncthreads();
  for(int off = 128; off > 0; off >>= 1){
    if(t < off) sm[t] += sm[t + off];
    __syncthreads();
  }
  if(t == 0) bsum[blockIdx.x] = sm[0];
}

// scan2 with internal bsum prefix (scanb folded in); nb <= 256.
__global__ __launch_bounds__(256) void scan2_kernel(const int* __restrict__ cnt,
                                                    const int* __restrict__ bsum,
                                                    int* __restrict__ rowptr,
                                                    int* __restrict__ cursor,
                                                    int N, int Etot, int nb){
  __shared__ int sm[256];
  __shared__ int spfx;
  int t = threadIdx.x;
  int c = blockIdx.x;
  // prefix = sum of bsum[0..c)
  sm[t] = (t < c && t < nb) ? bsum[t] : 0;
  __syncthreads();
  for(int off = 128; off > 0; off >>= 1){
    if(t < off) sm[t] += sm[t + off];
    __syncthreads();
  }
  if(t == 0) spfx = sm[0];
  __syncthreads();
  int pfx = spfx;
  __syncthreads();
  // chunk-local exclusive scan
  int i = c * 256 + t;
  int v = (i < N) ? cnt[i] : 0;
  sm[t] = v;
  __syncthreads();
  for(int off = 1; off < 256; off <<= 1){
    int x = 0;
    if(t >= off) x = sm[t - off];
    __syncthreads();
    sm[t] += x;
    __syncthreads();
  }
  if(i < N){
    int ex = sm[t] - v + pfx;
    rowptr[i] = ex;
    cursor[i] = ex;
    if(i == N - 1) rowptr[N] = Etot;
  }
}

__global__ __launch_bounds__(256) void scatter_kernel(const int* __restrict__ ei,
                                                      int* __restrict__ cursor,
                                                      int* __restrict__ esrc,
                                                      int E, int Etot){
  int e = blockIdx.x * 256 + threadIdx.x;
  if(e >= Etot) return;
  int s, d;
  if(e < E){ s = ei[e]; d = ei[E + e]; } else { s = e - E; d = s; }
  int pos = atomicAdd(&cursor[d], 1);
  esrc[pos] = s;
}

// ---------------- GEMM0: h0b[M,256] = bf16(x[M,256] @ W0) + logits ----------
// A staged directly from fp32 x (f2b during LDS fill) — no xb round-trip.
#define SKP 264   // padded LDS k-stride (shorts)
__global__ __launch_bounds__(256) void gemm0_kernel(const float4* __restrict__ x4,
                                                    const ushort_t* __restrict__ Bp,
                                                    ushort_t* __restrict__ h0b,
                                                    const float* __restrict__ asrc,
                                                    const float* __restrict__ adst,
                                                    float* __restrict__ als,
                                                    float* __restrict__ ald, int M){
  __shared__ ushort_t As[32 * SKP];
  int t = threadIdx.x;
  int row0 = blockIdx.x * 32;
  {
    int c = t;
    #pragma unroll
    for(int it = 0; it < 4; it++, c += 256){
      int r = c >> 5;
      int kc = (c & 31) << 3;          // col in shorts (multiple of 8)
      int gr = row0 + r;
      short8 v = {};
      if(gr < M){
        float4 f0 = x4[(size_t)gr * 64 + (kc >> 2)];
        float4 f1 = x4[(size_t)gr * 64 + (kc >> 2) + 1];
        v[0] = (short)f2b(f0.x); v[1] = (short)f2b(f0.y);
        v[2] = (short)f2b(f0.z); v[3] = (short)f2b(f0.w);
        v[4] = (short)f2b(f1.x); v[5] = (short)f2b(f1.y);
        v[6] = (short)f2b(f1.z); v[7] = (short)f2b(f1.w);
      }
      *(short8*)(As + r * SKP + kc) = v;
    }
  }
  __syncthreads();
  int wave = t >> 6, lane = t & 63;
  int m = lane & 15, q = lane >> 4;
  int colb = wave;                   // head
  const ushort_t* Bq = Bp + (size_t)(colb * 64 + m) * 256 + q * 8;
  const ushort_t* A0 = As + m * SKP + q * 8;
  const ushort_t* A1 = As + (16 + m) * SKP + q * 8;
  f32x4 acc[2][4] = {};
  for(int k0 = 0; k0 < 256; k0 += 32){
    short8 bv[4];
    #pragma unroll
    for(int j = 0; j < 4; j++) bv[j] = *(const short8*)(Bq + (size_t)j * 16 * 256 + k0);
    short8 a0 = *(const short8*)(A0 + k0);
    short8 a1 = *(const short8*)(A1 + k0);
    #pragma unroll
    for(int j = 0; j < 4; j++){
      acc[0][j] = __builtin_amdgcn_mfma_f32_16x16x32_bf16(a0, bv[j], acc[0][j], 0, 0, 0);
      acc[1][j] = __builtin_amdgcn_mfma_f32_16x16x32_bf16(a1, bv[j], acc[1][j], 0, 0, 0);
    }
  }
  #pragma unroll
  for(int rt = 0; rt < 2; rt++){
    #pragma unroll
    for(int j = 0; j < 4; j++){
      int col = colb * 64 + j * 16 + m;
      #pragma unroll
      for(int i = 0; i < 4; i++){
        int gr = row0 + rt * 16 + q * 4 + i;
        if(gr < M) h0b[(size_t)gr * 256 + col] = f2b(acc[rt][j][i]);
      }
    }
    float vs[4] = {0,0,0,0}, vd[4] = {0,0,0,0};
    #pragma unroll
    for(int j = 0; j < 4; j++){
      int col = colb * 64 + j * 16 + m;
      float a_s = asrc[col], a_d = adst[col];
      #pragma unroll
      for(int i = 0; i < 4; i++){
        vs[i] = fmaf(acc[rt][j][i], a_s, vs[i]);
        vd[i] = fmaf(acc[rt][j][i], a_d, vd[i]);
      }
    }
    #pragma unroll
    for(int off = 8; off > 0; off >>= 1){
      #pragma unroll
      for(int i = 0; i < 4; i++){
        vs[i] += __shfl_down(vs[i], off, 16);
        vd[i] += __shfl_down(vd[i], off, 16);
      }
    }
    if(m == 0){
      #pragma unroll
      for(int i = 0; i < 4; i++){
        int gr = row0 + rt * 16 + q * 4 + i;
        if(gr < M){
          als[(size_t)gr * 4 + colb] = vs[i];
          ald[(size_t)gr * 4 + colb] = vd[i];
        }
      }
    }
  }
}

// ---------------- agg0 + GEMM1 fused (16 nodes/block, r18 geometry) ----------
// Phase 1: wave w gathers nodes nbase+w*4..w*4+3 sequentially; h1 rows -> LDS.
// Phase 2: full 16x256 A tile; wave w computes cols w*16..w*16+15 via 8 MFMA;
//          emits g1b + layer-1 logits.
#define SKP2 264
__global__ __launch_bounds__(256, 8) void agg0g1_kernel(const int* __restrict__ rowptr,
                                                        const int* __restrict__ esrc,
                                                        const uint2* __restrict__ h0b2,
                                                        const float4* __restrict__ als4,
                                                        const float4* __restrict__ ald4,
                                                        const float4* __restrict__ b4,
                                                        const ushort_t* __restrict__ W1p,
                                                        const float* __restrict__ as1,
                                                        const float* __restrict__ ad1,
                                                        ushort_t* __restrict__ g1b,
                                                        float* __restrict__ als1,
                                                        float* __restrict__ ald1, int N){
  __shared__ ushort_t Hs[16 * SKP2];
  __shared__ float aps[4][16], apd[4][16];
  int t = threadIdx.x;
  int lane = t & 63;
  int wave = t >> 6;
  int nbase = blockIdx.x * 16;
  int h = lane >> 4;
  float4 bb = b4[lane];
  for(int j = 0; j < 4; j++){
    int n = nbase + wave * 4 + j;
    int nl = wave * 4 + j;
    uint2 o; o.x = 0u; o.y = 0u;
    if(n < N){
      int beg = rowptr[n], end = rowptr[n + 1];
      float adh = ((const float*)(ald4 + n))[h];
      float4 acc = make_float4(0.f, 0.f, 0.f, 0.f);
      float den = 0.f;
      for(int c0 = beg; c0 < end; c0 += 16){
        int e = c0 + (lane & 15);
        int s = n; float w = 0.f;
        if(e < end){
          s = esrc[e];
          w = expf(lrelu_f(((const float*)(als4 + s))[h] + adh));
        }
        int rem = end - c0;               // wave-uniform
        if(rem > 16) rem = 16;
        #pragma unroll
        for(int g = 0; g < 4; g++){
          if(g * 4 < rem){
            int si[4]; float wi[4]; uint2 v[4];
            #pragma unroll
            for(int ii = 0; ii < 4; ii++){
              int idx = (lane & 48) + g * 4 + ii;
              si[ii] = __shfl(s, idx, 64);
              wi[ii] = __shfl(w, idx, 64);
            }
            #pragma unroll
            for(int ii = 0; ii < 4; ii++)
              v[ii] = h0b2[((size_t)si[ii] << 6) + lane];
            #pragma unroll
            for(int ii = 0; ii < 4; ii++){
              acc.x = fmaf(wi[ii], b2f_lo(v[ii].x), acc.x);
              acc.y = fmaf(wi[ii], b2f_hi(v[ii].x), acc.y);
              acc.z = fmaf(wi[ii], b2f_lo(v[ii].y), acc.z);
              acc.w = fmaf(wi[ii], b2f_hi(v[ii].y), acc.w);
              den += wi[ii];
            }
          }
        }
      }
      float inv = 1.f / (den + 1e-16f);
      float v0 = elu_f(acc.x * inv + bb.x);
      float v1 = elu_f(acc.y * inv + bb.y);
      float v2 = elu_f(acc.z * inv + bb.z);
      float v3 = elu_f(acc.w * inv + bb.w);
      o.x = (unsigned)f2b(v0) | ((unsigned)f2b(v1) << 16);
      o.y = (unsigned)f2b(v2) | ((unsigned)f2b(v3) << 16);
    }
    *(uint2*)(Hs + nl * SKP2 + lane * 4) = o;
  }
  __syncthreads();
  // ---- phase 2: g1[16x64] = h1[16x256] @ W1 (per-wave 16-col quadrant) ----
  int m = lane & 15, q = lane >> 4;
  const ushort_t* Bw = W1p + (size_t)(wave * 16 + m) * 256 + q * 8;
  const ushort_t* Aw = Hs + m * SKP2 + q * 8;
  f32x4 acc1 = {};
  #pragma unroll
  for(int k0 = 0; k0 < 256; k0 += 32){
    short8 av = *(const short8*)(Aw + k0);
    short8 bv = *(const short8*)(Bw + k0);
    acc1 = __builtin_amdgcn_mfma_f32_16x16x32_bf16(av, bv, acc1, 0, 0, 0);
  }
  #pragma unroll
  for(int i = 0; i < 4; i++){
    int gn = nbase + q * 4 + i;
    if(gn < N) g1b[(size_t)gn * 64 + wave * 16 + m] = f2b(acc1[i]);
  }
  float a_s = as1[wave * 16 + m], a_d = ad1[wave * 16 + m];
  float vs[4], vd[4];
  #pragma unroll
  for(int i = 0; i < 4; i++){
    vs[i] = acc1[i] * a_s;
    vd[i] = acc1[i] * a_d;
  }
  #pragma unroll
  for(int off = 8; off > 0; off >>= 1){
    #pragma unroll
    for(int i = 0; i < 4; i++){
      vs[i] += __shfl_down(vs[i], off, 16);
      vd[i] += __shfl_down(vd[i], off, 16);
    }
  }
  if(m == 0){
    #pragma unroll
    for(int i = 0; i < 4; i++){
      aps[wave][q * 4 + i] = vs[i];
      apd[wave][q * 4 + i] = vd[i];
    }
  }
  __syncthreads();
  if(t < 16){
    int gn = nbase + t;
    if(gn < N){
      als1[gn] = aps[0][t] + aps[1][t] + aps[2][t] + aps[3][t];
      ald1[gn] = apd[0][t] + apd[1][t] + apd[2][t] + apd[3][t];
    }
  }
}

// ---------------- agg1-L1 + GEMM2 fused --------------------------------------
// L1 agg: one node per 16-lane group (4 nodes/wave, 16 nodes/block).
#define H2S 72    // LDS h2 tile k-stride (shorts)
__global__ __launch_bounds__(256, 8) void agg1g2_kernel(const int* __restrict__ rowptr,
                                                        const int* __restrict__ esrc,
                                                        const uint2* __restrict__ g1b2,
                                                        const float* __restrict__ als1,
                                                        const float* __restrict__ ald1,
                                                        const float* __restrict__ b1,
                                                        const ushort_t* __restrict__ W2p,
                                                        const float* __restrict__ as2,
                                                        const float* __restrict__ ad2,
                                                        ushort_t* __restrict__ g2b,
                                                        float* __restrict__ als2,
                                                        float* __restrict__ ald2, int N){
  __shared__ ushort_t Hs[16 * H2S];
  __shared__ float aps[4][16], apd[4][16];
  int t = threadIdx.x;
  int wave = t >> 6, lane = t & 63;
  int nbase = blockIdx.x * 16;
  int g = lane >> 4;                 // group in wave
  int p = lane & 15;                 // lane in group
  int n = nbase + wave * 4 + g;
  int nl = wave * 4 + g;
  if(n < N){
    int beg = rowptr[n], end = rowptr[n + 1];
    float ad = ald1[n];
    float4 acc = make_float4(0.f, 0.f, 0.f, 0.f);
    float den = 0.f;
    for(int c0 = beg; c0 < end; c0 += 16){
      int e = c0 + p;
      int s = n; float w = 0.f;
      if(e < end){
        s = esrc[e];
        w = expf(lrelu_f(als1[s] + ad));
      }
      int rem = end - c0;            // group-uniform
      if(rem > 16) rem = 16;
      #pragma unroll
      for(int gg = 0; gg < 4; gg++){
        if(gg * 4 < rem){
          #pragma unroll
          for(int ii = 0; ii < 4; ii++){
            int i = gg * 4 + ii;
            int idx = (lane & 48) + i;
            int si = __shfl(s, idx, 64);
            float wi = __shfl(w, idx, 64);
            uint2 v = g1b2[((size_t)si << 4) + p];
            acc.x = fmaf(wi, b2f_lo(v.x), acc.x);
            acc.y = fmaf(wi, b2f_hi(v.x), acc.y);
            acc.z = fmaf(wi, b2f_lo(v.y), acc.z);
            acc.w = fmaf(wi, b2f_hi(v.y), acc.w);
            den += wi;
          }
        }
      }
    }
    float inv = 1.f / (den + 1e-16f);
    float4 bb = ((const float4*)b1)[p];
    unsigned o0 = (unsigned)f2b(elu_f(acc.x * inv + bb.x)) |
                  ((unsigned)f2b(elu_f(acc.y * inv + bb.y)) << 16);
    unsigned o1 = (unsigned)f2b(elu_f(acc.z * inv + bb.z)) |
                  ((unsigned)f2b(elu_f(acc.w * inv + bb.w)) << 16);
    uint2 ov; ov.x = o0; ov.y = o1;
    *(uint2*)(Hs + nl * H2S + p * 4) = ov;
  }
  __syncthreads();
  int m = lane & 15, q = lane >> 4;
  const ushort_t* Bw = W2p + (size_t)(wave * 16 + m) * 64 + q * 8;
  const ushort_t* Aw = Hs + m * H2S + q * 8;
  f32x4 acc = {};
  #pragma unroll
  for(int k0 = 0; k0 < 64; k0 += 32){
    short8 av = *(const short8*)(Aw + k0);
    short8 bv = *(const short8*)(Bw + k0);
    acc = __builtin_amdgcn_mfma_f32_16x16x32_bf16(av, bv, acc, 0, 0, 0);
  }
  float a_s = as2[wave * 16 + m], a_d = ad2[wave * 16 + m];
  float vs[4], vd[4];
  #pragma unroll
  for(int i = 0; i < 4; i++){
    int gn = nbase + q * 4 + i;
    if(gn < N) g2b[(size_t)gn * 64 + wave * 16 + m] = f2b(acc[i]);
    vs[i] = acc[i] * a_s;
    vd[i] = acc[i] * a_d;
  }
  #pragma unroll
  for(int off = 8; off > 0; off >>= 1){
    #pragma unroll
    for(int i = 0; i < 4; i++){
      vs[i] += __shfl_down(vs[i], off, 16);
      vd[i] += __shfl_down(vd[i], off, 16);
    }
  }
  if(m == 0){
    #pragma unroll
    for(int i = 0; i < 4; i++){
      aps[wave][q * 4 + i] = vs[i];
      apd[wave][q * 4 + i] = vd[i];
    }
  }
  __syncthreads();
  if(t < 16){
    int gn = nbase + t;
    if(gn < N){
      als2[gn] = aps[0][t] + aps[1][t] + aps[2][t] + aps[3][t];
      ald2[gn] = apd[0][t] + apd[1][t] + apd[2][t] + apd[3][t];
    }
  }
}

// ---------------- final agg (layer 2): 16-lane group per node, fp32 out ------
__global__ __launch_bounds__(256, 8) void aggF_kernel(const int* __restrict__ rowptr,
                                                      const int* __restrict__ esrc,
                                                      const uint2* __restrict__ gb2,
                                                      const float* __restrict__ als,
                                                      const float* __restrict__ ald,
                                                      const float* __restrict__ b,
                                                      float4* __restrict__ outp, int N){
  int t = threadIdx.x;
  int lane = t & 63;
  int g = lane >> 4;
  int p = lane & 15;
  int n = blockIdx.x * 16 + (t >> 6) * 4 + g;
  if(n >= N) return;
  int beg = rowptr[n], end = rowptr[n + 1];
  float ad = ald[n];
  float4 acc = make_float4(0.f, 0.f, 0.f, 0.f);
  float den = 0.f;
  for(int c0 = beg; c0 < end; c0 += 16){
    int e = c0 + p;
    int s = n; float w = 0.f;
    if(e < end){
      s = esrc[e];
      w = expf(lrelu_f(als[s] + ad));
    }
    int rem = end - c0;              // group-uniform
    if(rem > 16) rem = 16;
    #pragma unroll
    for(int gg = 0; gg < 4; gg++){
      if(gg * 4 < rem){
        #pragma unroll
        for(int ii = 0; ii < 4; ii++){
          int i = gg * 4 + ii;
          int idx = (lane & 48) + i;
          int si = __shfl(s, idx, 64);
          float wi = __shfl(w, idx, 64);
          uint2 v = gb2[((size_t)si << 4) + p];
          acc.x = fmaf(wi, b2f_lo(v.x), acc.x);
          acc.y = fmaf(wi, b2f_hi(v.x), acc.y);
          acc.z = fmaf(wi, b2f_lo(v.y), acc.z);
          acc.w = fmaf(wi, b2f_hi(v.y), acc.w);
          den += wi;
        }
      }
    }
  }
  float inv = 1.f / (den + 1e-16f);
  float4 bb = ((const float4*)b)[p];
  float4 o;
  o.x = elu_f(acc.x * inv + bb.x);
  o.y = elu_f(acc.y * inv + bb.y);
  o.z = elu_f(acc.z * inv + bb.z);
  o.w = elu_f(acc.w * inv + bb.w);
  outp[((size_t)n << 4) + p] = o;
}

extern "C" void kernel_launch(void* const* d_in, const int* in_sizes, int n_in,
                              void* d_out, int out_size, void* d_ws, size_t ws_size,
                              hipStream_t stream){
  const float* x   = (const float*)d_in[0];
  const int*   ei  = (const int*)d_in[1];
  const float* W0  = (const float*)d_in[2];
  const float* as0 = (const float*)d_in[3];
  const float* ad0 = (const float*)d_in[4];
  const float* b0  = (const float*)d_in[5];
  const float* W1  = (const float*)d_in[6];
  const float* as1 = (const float*)d_in[7];
  const float* ad1 = (const float*)d_in[8];
  const float* b1  = (const float*)d_in[9];
  const float* W2  = (const float*)d_in[10];
  const float* as2 = (const float*)d_in[11];
  const float* ad2 = (const float*)d_in[12];
  const float* b2  = (const float*)d_in[13];
  int N = in_sizes[0] / 256;
  int E = in_sizes[1] / 2;
  int Etot = E + N;

  size_t off = 0;
  auto alc = [&](size_t bytes) -> char* {
    char* p = (char*)d_ws + off;
    off += (bytes + 255) & ~(size_t)255;
    return p;
  };
  ushort_t* g1b   = (ushort_t*)alc((size_t)N * 64 * 2);  // layer-1 gemm out
  ushort_t* h0b   = (ushort_t*)alc((size_t)N * 256 * 2); // h0 bf16; g2b aliases
  float*    als   = (float*)alc((size_t)N * 4 * 4);
  float*    ald   = (float*)alc((size_t)N * 4 * 4);
  float*    als1  = (float*)alc((size_t)N * 4);
  float*    ald1  = (float*)alc((size_t)N * 4);
  float*    als2  = (float*)alc((size_t)N * 4);
  float*    ald2  = (float*)alc((size_t)N * 4);
  int*      esrc  = (int*)alc((size_t)Etot * 4);
  int*      rowptr= (int*)alc((size_t)(N + 1) * 4);
  int*      cnt   = (int*)alc((size_t)N * 4);
  int*      cursor= (int*)alc((size_t)N * 4);
  int*      bsum  = (int*)alc(256 * 4);
  ushort_t* W0p   = (ushort_t*)alc(256 * 256 * 2);
  ushort_t* W1p   = (ushort_t*)alc(256 * 64 * 2);
  ushort_t* W2p   = (ushort_t*)alc(64 * 64 * 2);

  ushort_t* g2b = h0b;                     // h0b dead after agg0g1

  int nb = (N + 255) / 256;                // <= 256 chunks
  int eb = (Etot + 255) / 256;
  int g0b = (N + 31) / 32;
  int tb = (N + 15) / 16;
  int ab16 = (N + 15) / 16;

  // ---- prep + CSR build ----
  hipMemsetAsync(cnt, 0, (size_t)N * 4, stream);
  prep_kernel<<<eb + 336, 256, 0, stream>>>(ei, cnt, W0, W0p, W1, W1p, W2, W2p,
                                            E, Etot, eb);
  blocksum_kernel<<<nb, 256, 0, stream>>>(cnt, bsum, N);
  scan2_kernel<<<nb, 256, 0, stream>>>(cnt, bsum, rowptr, cursor, N, Etot, nb);
  scatter_kernel<<<eb, 256, 0, stream>>>(ei, cursor, esrc, E, Etot);

  // ---- Layer 0 GEMM (reads x fp32 directly) ----
  gemm0_kernel<<<g0b, 256, 0, stream>>>((const float4*)x, W0p, h0b,
                                        as0, ad0, als, ald, N);

  // ---- Layer 0 agg + Layer 1 GEMM (fused, 16 nodes/block) ----
  agg0g1_kernel<<<ab16, 256, 0, stream>>>(rowptr, esrc, (const uint2*)h0b,
                                          (const float4*)als, (const float4*)ald,
                                          (const float4*)b0, W1p, as1, ad1,
                                          g1b, als1, ald1, N);

  // ---- Layer 1 agg + Layer 2 GEMM (fused) ----
  agg1g2_kernel<<<tb, 256, 0, stream>>>(rowptr, esrc, (const uint2*)g1b,
                                        als1, ald1, b1, W2p, as2, ad2,
                                        g2b, als2, ald2, N);

  // ---- Layer 2 agg -> output ----
  aggF_kernel<<<ab16, 256, 0, stream>>>(rowptr, esrc, (const uint2*)g2b,
                                        als2, ald2, b2, (float4*)d_out, N);
}